// Round 13
// baseline (90.837 us; speedup 1.0000x reference)
//
#include <hip/hip_runtime.h>
#include <hip/hip_bf16.h>
#include <math.h>

#define BATCH 32
#define LEN   2048
#define HID   128
#define SSM   256

#define BPL 32768                     // elements per B-split plane (256*128)

typedef __attribute__((ext_vector_type(4))) float f32x4;
typedef __attribute__((ext_vector_type(8))) short bf16x8;
typedef __attribute__((ext_vector_type(4))) int   i32x4;

// RNE f32->bf16 (bit trick)
static __device__ __forceinline__ unsigned short f2bf(float x) {
    union { float f; unsigned u; } v; v.f = x;
    unsigned r = (v.u + 0x7FFFu + ((v.u >> 16) & 1u)) >> 16;
    return (unsigned short)r;
}
// truncating f32->bf16 (hi term of split; lo captures remainder exactly)
static __device__ __forceinline__ unsigned short f2bf_hi(float x) {
    union { float f; unsigned u; } v; v.f = x;
    return (unsigned short)(v.u >> 16);
}
static __device__ __forceinline__ float bf2f(unsigned short b) {
    union { unsigned u; float f; } v; v.u = ((unsigned)b) << 16;
    return v.f;
}
// packed RNE pair convert -> one u32 (v_cvt_pk_bf16_f32); lo half = first arg
static __device__ __forceinline__ unsigned int cvtpk(float a, float b) {
    __hip_bfloat162 h = __float22bfloat162_rn(float2{a, b});
    union { __hip_bfloat162 h2; unsigned int u; } c; c.h2 = h;
    return c.u;
}
static __device__ __forceinline__ void cmul(float& rr, float& ri,
                                            float ar, float ai, float br, float bi) {
    rr = ar * br - ai * bi;
    ri = ar * bi + ai * br;
}
// async global->LDS 16B (zero VGPR round-trip; vmcnt-counted)
static __device__ __forceinline__ void gload16(const void* g, void* l) {
    __builtin_amdgcn_global_load_lds(
        (const __attribute__((address_space(1))) unsigned int*)g,
        (__attribute__((address_space(3))) unsigned int*)l,
        16, 0, 0);
}

// ---------------------------------------------------------------------------
// K0b: pre-split B (hi/lo planes, [p][h]) and C2 (kappa-interleaved GEMM
// operand: C2[hilo][h][kappa=2p+comp] with re at even kappa, NEGATED im at
// odd kappa). Block 256 computes lam.
// ---------------------------------------------------------------------------
__global__ __launch_bounds__(256) void k0b_prep(const float* __restrict__ Bm,
                                                const float* __restrict__ Cm,
                                                const float* __restrict__ A,
                                                const float* __restrict__ G,
                                                const float* __restrict__ steps,
                                                unsigned short* __restrict__ Bsp,
                                                unsigned short* __restrict__ C2,
                                                float* __restrict__ lam) {
    if (blockIdx.x == 256) {
        int p = threadIdx.x;
        if (p < SSM) {
            float stp   = 1.f / (1.f + expf(-steps[p]));
            float g     = fmaxf(G[p], 0.f);
            float denom = fmaxf(stp * stp, 1e-6f);
            float s     = stp * g;
            float base  = sqrtf(fmaxf(1.f + s, 1e-6f));
            float alow  = (2.f + s - 2.f * base) / denom;
            float ahigh = (2.f + s + 2.f * base) / denom;
            float a     = alow + fmaxf(A[p] - alow, 0.f) - fmaxf(A[p] - ahigh, 0.f);
            float S     = 1.f / (1.f + stp * g);
            float T     = S + 1.f - stp * stp * S * a;
            lam[p]       = 0.5f * T;
            lam[SSM + p] = sqrtf(fmaxf(S - 0.25f * T * T, 0.f));
        }
        return;
    }
    int gidx = blockIdx.x * 256 + threadIdx.x;
    if (gidx < 32768) {
        int p = gidx >> 7, h = gidx & 127;
        float vr = Bm[(size_t)(p * HID + h) * 2];
        float vi = Bm[(size_t)(p * HID + h) * 2 + 1];
        unsigned short hh = f2bf_hi(vr);
        Bsp[0 * BPL + p * HID + h] = hh;
        Bsp[1 * BPL + p * HID + h] = f2bf(vr - bf2f(hh));
        hh = f2bf_hi(vi);
        Bsp[2 * BPL + p * HID + h] = hh;
        Bsp[3 * BPL + p * HID + h] = f2bf(vi - bf2f(hh));
    } else {
        int g2 = gidx - 32768;
        int h = g2 >> 8, p = g2 & 255;
        float vr = Cm[(size_t)(h * SSM + p) * 2];
        float vi = -Cm[(size_t)(h * SSM + p) * 2 + 1];
        unsigned short rh = f2bf_hi(vr);
        unsigned short ih = f2bf_hi(vi);
        size_t rowh = (size_t)h * 512;
        C2[rowh + 2 * p]               = rh;
        C2[rowh + 2 * p + 1]           = ih;
        C2[65536 + rowh + 2 * p]       = f2bf(vr - bf2f(rh));
        C2[65536 + rowh + 2 * p + 1]   = f2bf(vi - bf2f(ih));
    }
}

// ---------------------------------------------------------------------------
// KU: stream-convert u (f32) -> ubf (bf16 RNE), same [b][l][h] layout.
// ---------------------------------------------------------------------------
__global__ __launch_bounds__(256) void ku_cvt(const float* __restrict__ u,
                                              unsigned short* __restrict__ ubf) {
    const int total = BATCH * LEN * HID;
    const int stride = 2048 * 256 * 8;
    for (int i = (blockIdx.x * 256 + threadIdx.x) * 8; i < total; i += stride) {
        f32x4 a = *(const f32x4*)&u[i];
        f32x4 c = *(const f32x4*)&u[i + 4];
        i32x4 o;
        o[0] = (int)cvtpk(a[0], a[1]);
        o[1] = (int)cvtpk(a[2], a[3]);
        o[2] = (int)cvtpk(c[0], c[1]);
        o[3] = (int)cvtpk(c[2], c[3]);
        *(i32x4*)&ubf[i] = o;
    }
}

// ---------------------------------------------------------------------------
// K12 v10: R12's verified kernel (48 us), with states written to the
// kappa-interleaved TP[b][l][512] layout: sT2 staging = 4 cvtpk u32 writes
// per lane (re,im adjacent = one u32); stores 64B-contiguous per row.
// Everything upstream (staging/GEMM/split-scan) byte-identical to R12.
// ---------------------------------------------------------------------------
__global__ __launch_bounds__(512, 4) void k12_fused(const unsigned short* __restrict__ ubf,
                                                    const unsigned short* __restrict__ Bsp,
                                                    const float* __restrict__ lam,
                                                    unsigned short* __restrict__ TP) {
    __shared__ __align__(16) char sU[2][32768];   // dbuf: 128 rows x 256B
    __shared__ __align__(16) char sT2[10240];     // 128 rows x 80B (64 data + pad)
    __shared__ float Rld[4][2][8][2];             // [wl][wp][p8][re/im]

    int d    = blockIdx.x;           // 0..511
    int xcd  = d & 7;
    int idx  = d >> 3;               // 0..63
    int pt   = idx & 15;             // 16 p-tiles of 16
    int bhi  = idx >> 4;             // 0..3
    int b    = bhi * 8 + xcd;
    int p0   = pt * 16;

    int tid  = threadIdx.x;
    int lane = tid & 63, w = tid >> 6;
    int wl   = w >> 1, wp = w & 1;
    int fr   = lane & 15, g = lane >> 4;
    int frp  = fr & 7;               // p-column within octet
    int comp = fr >> 3;              // 0 = re-half (owns mi=0), 1 = im-half (owns mi=1)
    int pcol = p0 + wp * 8 + frp;    // this lane's p

    // ---- B fragments: lane's comp & p-col, hi/lo x 4 k-chunks ----
    const unsigned short* Bh  = Bsp + (size_t)(comp * 2) * BPL + (size_t)pcol * HID;
    const unsigned short* Blo = Bsp + (size_t)(comp * 2 + 1) * BPL + (size_t)pcol * HID;
    bf16x8 Bfh[4], Bfl[4];
#pragma unroll
    for (int kc = 0; kc < 4; ++kc) {
        Bfh[kc] = *(const bf16x8*)&Bh[kc * 32 + g * 8];
        Bfl[kc] = *(const bf16x8*)&Blo[kc * 32 + g * 8];
    }

    // ---- lambda powers for p = pcol ----
    float pw_r[4], pw_i[4];          // lam^(r+1)
    float lg_r, lg_i;                // lam^(4g)
    float l4r, l4i, l8r, l8i, l16r, l16i, l32r, l32i;
    {
        float ar = lam[pcol], ai = lam[SSM + pcol];
        pw_r[0] = ar; pw_i[0] = ai;
        cmul(pw_r[1], pw_i[1], ar, ai, ar, ai);
        cmul(pw_r[2], pw_i[2], pw_r[1], pw_i[1], ar, ai);
        cmul(pw_r[3], pw_i[3], pw_r[1], pw_i[1], pw_r[1], pw_i[1]);
        l4r = pw_r[3]; l4i = pw_i[3];
        cmul(l8r, l8i, l4r, l4i, l4r, l4i);
        cmul(l16r, l16i, l8r, l8i, l8r, l8i);
        cmul(l32r, l32i, l16r, l16i, l16r, l16i);
        if (g == 0)      { lg_r = 1.f; lg_i = 0.f; }
        else if (g == 1) { lg_r = l4r; lg_i = l4i; }
        else if (g == 2) { lg_r = l8r; lg_i = l8i; }
        else             { cmul(lg_r, lg_i, l8r, l8i, l4r, l4i); }
    }

    float TCr = 0.f, TCi = 0.f;      // running tile carry (per wp group)

    const unsigned short* ub = ubf + (size_t)b * (LEN * HID);
    int srow32  = tid >> 4;          // 0..31
    int stg_src = srow32 * HID + ((((tid & 15) * 16) ^ ((srow32 & 7) << 4)) >> 1);

#define STAGE(buf, tt)                                                        \
    {                                                                         \
        const unsigned short* gs = ub + (size_t)(tt) * 16384 + stg_src;       \
        char* ls = &sU[buf][tid * 16];                                        \
        _Pragma("unroll")                                                     \
        for (int q = 0; q < 4; ++q)                                           \
            gload16(gs + q * 4096, ls + q * 8192);                            \
    }

    // ---- prologue: stage tile 0, drain ----
    STAGE(0, 0)
    __syncthreads();
    int cur = 0;

    for (int t = 0; t < 16; ++t) {
        int l0t = t * 128;

        // ---- issue next tile's async staging (hidden under GEMM+scan) ----
        if (t < 15) STAGE(cur ^ 1, t + 1)

        // ---- GEMM: wave rows wl*32..wl*32+31; B packs [re|im] ----
        const char* su = &sU[cur][0];
        f32x4 acc[2];
        acc[0] = (f32x4)(0.f); acc[1] = (f32x4)(0.f);
#pragma unroll
        for (int kc = 0; kc < 4; ++kc) {
#pragma unroll
            for (int mi = 0; mi < 2; ++mi) {
                int off = (wl * 32 + mi * 16 + fr) * 256 + ((kc * 64 + g * 16) ^ ((fr & 7) << 4));
                bf16x8 ah = *(const bf16x8*)(su + off);
                acc[mi] = __builtin_amdgcn_mfma_f32_16x16x32_bf16(ah, Bfh[kc], acc[mi], 0, 0, 0);
                acc[mi] = __builtin_amdgcn_mfma_f32_16x16x32_bf16(ah, Bfl[kc], acc[mi], 0, 0, 0);
            }
        }

        // ---- split swap: each lane keeps ONLY its own mi (= comp) ----
        float xr[4], xi[4];
#pragma unroll
        for (int e = 0; e < 4; ++e) {
            float send = (comp == 0) ? acc[1][e] : acc[0][e];
            float oth  = __shfl_xor(send, 8, 64);
            xr[e] = (comp == 0) ? acc[0][e] : oth;
            xi[e] = (comp == 0) ? oth       : acc[1][e];
        }

        // ---- scan phase 1 (split): quad scan + g-scan on own fragment ----
        float Er, Ei, Fr, Fi, For, Foi;
        {
            float lr = pw_r[0], li = pw_i[0];
            float cr = 0.f, ci = 0.f;
#pragma unroll
            for (int r = 0; r < 4; ++r) {
                float nr = fmaf(lr, cr, fmaf(-li, ci, xr[r]));
                float ni = fmaf(lr, ci, fmaf(li, cr, xi[r]));
                cr = nr; ci = ni;
                xr[r] = cr; xi[r] = ci;
            }
            float Qr = cr, Qi = ci;
            float ur = __shfl_up(Qr, 16u, 64);
            float ui = __shfl_up(Qi, 16u, 64);
            if (g >= 1) {
                Qr = fmaf(l4r, ur, fmaf(-l4i, ui, Qr));
                Qi = fmaf(l4r, ui, fmaf(l4i, ur, Qi));
            }
            ur = __shfl_up(Qr, 32u, 64);
            ui = __shfl_up(Qi, 32u, 64);
            if (g >= 2) {
                Qr = fmaf(l8r, ur, fmaf(-l8i, ui, Qr));
                Qi = fmaf(l8r, ui, fmaf(l8i, ur, Qi));
            }
            Er = __shfl_up(Qr, 16u, 64);
            Ei = __shfl_up(Qi, 16u, 64);
            if (g == 0) { Er = 0.f; Ei = 0.f; }
            Fr = __shfl(Qr, fr + 48, 64);   // own-frag total carry
            Fi = __shfl(Qi, fr + 48, 64);
            For = __shfl_xor(Fr, 8, 64);    // partner-frag carry
            Foi = __shfl_xor(Fi, 8, 64);
            float Rr = fmaf(l16r, For, fmaf(-l16i, Foi, Fr));
            float Ri = fmaf(l16r, Foi, fmaf(l16i, For, Fi));
            if (g == 0 && fr >= 8) { Rld[wl][wp][frp][0] = Rr; Rld[wl][wp][frp][1] = Ri; }
        }
        __syncthreads();   // bar2: Rld ready; sU[cur] reads done; staging drained

        // ---- scan phase 2: cross-wave lam^32 chain; own-mi corrections ----
        {
            float Wr = TCr, Wi = TCi;
            float Tr = TCr, Ti = TCi;
#pragma unroll
            for (int w2 = 0; w2 < 4; ++w2) {
                float rr = Rld[w2][wp][frp][0], ri = Rld[w2][wp][frp][1];
                float nTr = fmaf(l32r, Tr, fmaf(-l32i, Ti, rr));
                float nTi = fmaf(l32r, Ti, fmaf(l32i, Tr, ri));
                Tr = nTr; Ti = nTi;
                if (w2 < wl) {
                    float nWr = fmaf(l32r, Wr, fmaf(-l32i, Wi, rr));
                    float nWi = fmaf(l32r, Wi, fmaf(l32i, Wr, ri));
                    Wr = nWr; Wi = nWi;
                }
            }
            TCr = Tr; TCi = Ti;
            float prr, pri;
            if (comp == 0) { prr = Wr; pri = Wi; }
            else {
                prr = fmaf(l16r, Wr, fmaf(-l16i, Wi, For));
                pri = fmaf(l16r, Wi, fmaf(l16i, Wr, Foi));
            }
            float Mr = fmaf(lg_r, prr, fmaf(-lg_i, pri, Er));
            float Mi = fmaf(lg_r, pri, fmaf(lg_i, prr, Ei));
#pragma unroll
            for (int r = 0; r < 4; ++r) {
                xr[r] = fmaf(pw_r[r], Mr, fmaf(-pw_i[r], Mi, xr[r]));
                xi[r] = fmaf(pw_r[r], Mi, fmaf(pw_i[r], Mr, xi[r]));
            }
        }

        // ---- stage into sT2 [128 rows(l)][16 u32(kappa-pairs)+pad] ----
        {
            int colb  = wl * 32 + comp * 16 + g * 4;
            int idxu  = wp * 8 + frp;            // u32 index = local p
            int piece = idxu >> 2, sub = idxu & 3;
            int pw    = piece ^ g;               // swizzle key (row>>2)&3 == g
#pragma unroll
            for (int r = 0; r < 4; ++r) {
                unsigned int pk = cvtpk(xr[r], xi[r]);   // lo=re, hi=im
                *(unsigned int*)(sT2 + (colb + r) * 80 + pw * 16 + sub * 4) = pk;
            }
        }
        __syncthreads();   // bar3: sT2 ready

        // ---- stores: 128 rows x 64B contiguous into TP ----
        {
            int row = tid >> 2, q = tid & 3;
            int x2  = (row >> 2) & 3;
            bf16x8 v = *(const bf16x8*)(sT2 + row * 80 + ((q ^ x2) * 16));
            *(bf16x8*)&TP[((size_t)(b * LEN) + l0t + row) * 512 + p0 * 2 + q * 8] = v;
        }
        cur ^= 1;
    }
#undef STAGE
}

// ---------------------------------------------------------------------------
// K3 v2: flat real GEMM  out[b][l][h] = sum_{kappa=0..511} TP[b][l][k]*C2[..][h][k]
//        (+ u*D).  M=l (128), N=h (64, h-split), K=512 in 16 chunks of 32.
// A and B staged via global_load_lds (swizzle pre-folded into source),
// double-buffered, 1 barrier/chunk. 1024 blocks x 256 thr, 4 blocks/CU.
// ---------------------------------------------------------------------------
__global__ __launch_bounds__(256, 4) void k3_out(const unsigned short* __restrict__ TP,
                                                 const unsigned short* __restrict__ C2,
                                                 const unsigned short* __restrict__ ubf,
                                                 const float* __restrict__ D,
                                                 float* __restrict__ out) {
    __shared__ __align__(16) char sAB[2][16384];   // [buf]: A 8KB ([128 l][64B]) | C 8KB ([2 hilo][64 h][64B])

    int d    = blockIdx.x;            // 0..1023
    int xcd  = d & 7;
    int rest = d >> 3;                // 0..127
    int ht   = rest & 1;
    int lt   = (rest >> 1) & 15;
    int bhi  = rest >> 5;             // 0..3
    int b    = bhi * 8 + xcd;
    int l0   = lt * 128;
    int h0   = ht * 64;

    int tid = threadIdx.x;
    int lane = tid & 63, w = tid >> 6;
    int wl = w >> 1, wh = w & 1;
    int fr = lane & 15, g = lane >> 4;

    f32x4 acc[4][2];
#pragma unroll
    for (int mi = 0; mi < 4; ++mi)
#pragma unroll
        for (int ni = 0; ni < 2; ++ni) acc[mi][ni] = (f32x4)(0.f);

    float dv[2];
#pragma unroll
    for (int ni = 0; ni < 2; ++ni) dv[ni] = D[h0 + wh * 32 + ni * 16 + fr];

#define STAGE3(buf, cc)                                                       \
    {                                                                         \
        _Pragma("unroll")                                                     \
        for (int q = 0; q < 2; ++q) {                                         \
            int dg = tid + q * 256; int rw = dg >> 2, sl = dg & 3;            \
            gload16(TP + ((size_t)(b * LEN) + l0 + rw) * 512 + (cc) * 32 +    \
                        ((sl ^ (rw & 3)) * 8),                                \
                    &sAB[buf][dg * 16]);                                      \
        }                                                                     \
        _Pragma("unroll")                                                     \
        for (int q = 0; q < 2; ++q) {                                         \
            int dg = tid + q * 256; int hl = dg >> 8, hr = (dg >> 2) & 63;    \
            int sl = dg & 3;                                                  \
            gload16(C2 + ((size_t)(hl * 128 + h0 + hr)) * 512 + (cc) * 32 +   \
                        ((sl ^ (hr & 3)) * 8),                                \
                    &sAB[buf][8192 + dg * 16]);                               \
        }                                                                     \
    }

    STAGE3(0, 0)
    __syncthreads();
    int cur = 0;

    for (int c = 0; c < 16; ++c) {
        if (c < 15) STAGE3(cur ^ 1, c + 1)

        const char* sb = &sAB[cur][0];
        int swz = (g ^ (fr & 3)) * 16;
        bf16x8 bfr[2][2];
#pragma unroll
        for (int ni = 0; ni < 2; ++ni) {
            int hrow = wh * 32 + ni * 16 + fr;
#pragma unroll
            for (int hl = 0; hl < 2; ++hl)
                bfr[ni][hl] = *(const bf16x8*)(sb + 8192 + hl * 4096 + hrow * 64 + swz);
        }
#pragma unroll
        for (int mi = 0; mi < 4; ++mi) {
            int arow = wl * 64 + mi * 16 + fr;
            bf16x8 af = *(const bf16x8*)(sb + arow * 64 + swz);
#pragma unroll
            for (int ni = 0; ni < 2; ++ni) {
                acc[mi][ni] = __builtin_amdgcn_mfma_f32_16x16x32_bf16(af, bfr[ni][0], acc[mi][ni], 0, 0, 0);
                acc[mi][ni] = __builtin_amdgcn_mfma_f32_16x16x32_bf16(af, bfr[ni][1], acc[mi][ni], 0, 0, 0);
            }
        }
        __syncthreads();
        cur ^= 1;
    }
#undef STAGE3

#pragma unroll
    for (int mi = 0; mi < 4; ++mi)
#pragma unroll
        for (int ni = 0; ni < 2; ++ni) {
            int lb = l0 + wl * 64 + mi * 16 + g * 4;
            int h  = h0 + wh * 32 + ni * 16 + fr;
#pragma unroll
            for (int r = 0; r < 4; ++r) {
                size_t idx = ((size_t)b * LEN + lb + r) * HID + h;
                out[idx] = acc[mi][ni][r] + bf2f(ubf[idx]) * dv[ni];
            }
        }
}

// ---------------------------------------------------------------------------
// Workspace layout (bytes):
//   [0, 67108864)              TP: states, kappa-interleaved [b][l][512]
//   [67108864, 67110912)       lam (512 f32)
//   [67110912, 67373056)       B split planes (4 x 32768 ushort)
//   [67373056, 67635200)       C2 (2 hilo x 128 h x 512 kappa ushort)
//   [67635200, 84412416)       ubf: u as bf16 [b][l][h]
// ---------------------------------------------------------------------------
extern "C" void kernel_launch(void* const* d_in, const int* in_sizes, int n_in,
                              void* d_out, int out_size, void* d_ws, size_t ws_size,
                              hipStream_t stream) {
    const float* u  = (const float*)d_in[0];
    const float* A  = (const float*)d_in[1];
    const float* G  = (const float*)d_in[2];
    const float* st = (const float*)d_in[3];
    const float* B  = (const float*)d_in[4];
    const float* C  = (const float*)d_in[5];
    const float* D  = (const float*)d_in[6];
    float* out = (float*)d_out;

    char* WS = (char*)d_ws;
    unsigned short* TP  = (unsigned short*)WS;
    float* lam          = (float*)(WS + 67108864);
    unsigned short* Bsp = (unsigned short*)(WS + 67110912);
    unsigned short* C2  = (unsigned short*)(WS + 67373056);
    unsigned short* ubf = (unsigned short*)(WS + 67635200);

    k0b_prep<<<257, 256, 0, stream>>>(B, C, A, G, st, Bsp, C2, lam);
    ku_cvt<<<2048, 256, 0, stream>>>(u, ubf);
    k12_fused<<<512, 512, 0, stream>>>(ubf, Bsp, lam, TP);
    k3_out<<<1024, 256, 0, stream>>>(TP, C2, ubf, D, out);
}

// Round 14
// 86.437 us; speedup vs baseline: 1.0509x; 1.0509x over previous
//
#include <hip/hip_runtime.h>
#include <hip/hip_bf16.h>
#include <math.h>

#define BATCH 32
#define LEN   2048
#define HID   128
#define SSM   256

#define BPL 32768                     // elements per B-split plane (256*128)

typedef __attribute__((ext_vector_type(4))) float f32x4;
typedef __attribute__((ext_vector_type(8))) short bf16x8;
typedef __attribute__((ext_vector_type(4))) int   i32x4;

// RNE f32->bf16 (bit trick)
static __device__ __forceinline__ unsigned short f2bf(float x) {
    union { float f; unsigned u; } v; v.f = x;
    unsigned r = (v.u + 0x7FFFu + ((v.u >> 16) & 1u)) >> 16;
    return (unsigned short)r;
}
// truncating f32->bf16 (hi term of split; lo captures remainder exactly)
static __device__ __forceinline__ unsigned short f2bf_hi(float x) {
    union { float f; unsigned u; } v; v.f = x;
    return (unsigned short)(v.u >> 16);
}
static __device__ __forceinline__ float bf2f(unsigned short b) {
    union { unsigned u; float f; } v; v.u = ((unsigned)b) << 16;
    return v.f;
}
// packed RNE pair convert -> one u32 (v_cvt_pk_bf16_f32); lo half = first arg
static __device__ __forceinline__ unsigned int cvtpk(float a, float b) {
    __hip_bfloat162 h = __float22bfloat162_rn(float2{a, b});
    union { __hip_bfloat162 h2; unsigned int u; } c; c.h2 = h;
    return c.u;
}
static __device__ __forceinline__ void cmul(float& rr, float& ri,
                                            float ar, float ai, float br, float bi) {
    rr = ar * br - ai * bi;
    ri = ar * bi + ai * br;
}
// async global->LDS 16B (zero VGPR round-trip; vmcnt-counted)
static __device__ __forceinline__ void gload16(const void* g, void* l) {
    __builtin_amdgcn_global_load_lds(
        (const __attribute__((address_space(1))) unsigned int*)g,
        (__attribute__((address_space(3))) unsigned int*)l,
        16, 0, 0);
}

// ---------------------------------------------------------------------------
// K0b: pre-split B (hi/lo planes, [p][h]) and C2 (kappa-interleaved GEMM
// operand: C2[hilo][h][kappa=2p+comp] with re at even kappa, NEGATED im at
// odd kappa). Block 256 computes lam.  (verified R13)
// ---------------------------------------------------------------------------
__global__ __launch_bounds__(256) void k0b_prep(const float* __restrict__ Bm,
                                                const float* __restrict__ Cm,
                                                const float* __restrict__ A,
                                                const float* __restrict__ G,
                                                const float* __restrict__ steps,
                                                unsigned short* __restrict__ Bsp,
                                                unsigned short* __restrict__ C2,
                                                float* __restrict__ lam) {
    if (blockIdx.x == 256) {
        int p = threadIdx.x;
        if (p < SSM) {
            float stp   = 1.f / (1.f + expf(-steps[p]));
            float g     = fmaxf(G[p], 0.f);
            float denom = fmaxf(stp * stp, 1e-6f);
            float s     = stp * g;
            float base  = sqrtf(fmaxf(1.f + s, 1e-6f));
            float alow  = (2.f + s - 2.f * base) / denom;
            float ahigh = (2.f + s + 2.f * base) / denom;
            float a     = alow + fmaxf(A[p] - alow, 0.f) - fmaxf(A[p] - ahigh, 0.f);
            float S     = 1.f / (1.f + stp * g);
            float T     = S + 1.f - stp * stp * S * a;
            lam[p]       = 0.5f * T;
            lam[SSM + p] = sqrtf(fmaxf(S - 0.25f * T * T, 0.f));
        }
        return;
    }
    int gidx = blockIdx.x * 256 + threadIdx.x;
    if (gidx < 32768) {
        int p = gidx >> 7, h = gidx & 127;
        float vr = Bm[(size_t)(p * HID + h) * 2];
        float vi = Bm[(size_t)(p * HID + h) * 2 + 1];
        unsigned short hh = f2bf_hi(vr);
        Bsp[0 * BPL + p * HID + h] = hh;
        Bsp[1 * BPL + p * HID + h] = f2bf(vr - bf2f(hh));
        hh = f2bf_hi(vi);
        Bsp[2 * BPL + p * HID + h] = hh;
        Bsp[3 * BPL + p * HID + h] = f2bf(vi - bf2f(hh));
    } else {
        int g2 = gidx - 32768;
        int h = g2 >> 8, p = g2 & 255;
        float vr = Cm[(size_t)(h * SSM + p) * 2];
        float vi = -Cm[(size_t)(h * SSM + p) * 2 + 1];
        unsigned short rh = f2bf_hi(vr);
        unsigned short ih = f2bf_hi(vi);
        size_t rowh = (size_t)h * 512;
        C2[rowh + 2 * p]               = rh;
        C2[rowh + 2 * p + 1]           = ih;
        C2[65536 + rowh + 2 * p]       = f2bf(vr - bf2f(rh));
        C2[65536 + rowh + 2 * p + 1]   = f2bf(vi - bf2f(ih));
    }
}

// ---------------------------------------------------------------------------
// KU: stream-convert u (f32) -> ubf (bf16 RNE), same [b][l][h] layout.
// ---------------------------------------------------------------------------
__global__ __launch_bounds__(256) void ku_cvt(const float* __restrict__ u,
                                              unsigned short* __restrict__ ubf) {
    const int total = BATCH * LEN * HID;
    const int stride = 2048 * 256 * 8;
    for (int i = (blockIdx.x * 256 + threadIdx.x) * 8; i < total; i += stride) {
        f32x4 a = *(const f32x4*)&u[i];
        f32x4 c = *(const f32x4*)&u[i + 4];
        i32x4 o;
        o[0] = (int)cvtpk(a[0], a[1]);
        o[1] = (int)cvtpk(a[2], a[3]);
        o[2] = (int)cvtpk(c[0], c[1]);
        o[3] = (int)cvtpk(c[2], c[3]);
        *(i32x4*)&ubf[i] = o;
    }
}

// ---------------------------------------------------------------------------
// K12 v10 (verified R13, 48us): split-scan fused kernel, states written to
// kappa-interleaved TP[b][l][512].
// ---------------------------------------------------------------------------
__global__ __launch_bounds__(512, 4) void k12_fused(const unsigned short* __restrict__ ubf,
                                                    const unsigned short* __restrict__ Bsp,
                                                    const float* __restrict__ lam,
                                                    unsigned short* __restrict__ TP) {
    __shared__ __align__(16) char sU[2][32768];   // dbuf: 128 rows x 256B
    __shared__ __align__(16) char sT2[10240];     // 128 rows x 80B (64 data + pad)
    __shared__ float Rld[4][2][8][2];             // [wl][wp][p8][re/im]

    int d    = blockIdx.x;           // 0..511
    int xcd  = d & 7;
    int idx  = d >> 3;               // 0..63
    int pt   = idx & 15;             // 16 p-tiles of 16
    int bhi  = idx >> 4;             // 0..3
    int b    = bhi * 8 + xcd;
    int p0   = pt * 16;

    int tid  = threadIdx.x;
    int lane = tid & 63, w = tid >> 6;
    int wl   = w >> 1, wp = w & 1;
    int fr   = lane & 15, g = lane >> 4;
    int frp  = fr & 7;               // p-column within octet
    int comp = fr >> 3;              // 0 = re-half (owns mi=0), 1 = im-half (owns mi=1)
    int pcol = p0 + wp * 8 + frp;    // this lane's p

    // ---- B fragments: lane's comp & p-col, hi/lo x 4 k-chunks ----
    const unsigned short* Bh  = Bsp + (size_t)(comp * 2) * BPL + (size_t)pcol * HID;
    const unsigned short* Blo = Bsp + (size_t)(comp * 2 + 1) * BPL + (size_t)pcol * HID;
    bf16x8 Bfh[4], Bfl[4];
#pragma unroll
    for (int kc = 0; kc < 4; ++kc) {
        Bfh[kc] = *(const bf16x8*)&Bh[kc * 32 + g * 8];
        Bfl[kc] = *(const bf16x8*)&Blo[kc * 32 + g * 8];
    }

    // ---- lambda powers for p = pcol ----
    float pw_r[4], pw_i[4];          // lam^(r+1)
    float lg_r, lg_i;                // lam^(4g)
    float l4r, l4i, l8r, l8i, l16r, l16i, l32r, l32i;
    {
        float ar = lam[pcol], ai = lam[SSM + pcol];
        pw_r[0] = ar; pw_i[0] = ai;
        cmul(pw_r[1], pw_i[1], ar, ai, ar, ai);
        cmul(pw_r[2], pw_i[2], pw_r[1], pw_i[1], ar, ai);
        cmul(pw_r[3], pw_i[3], pw_r[1], pw_i[1], pw_r[1], pw_i[1]);
        l4r = pw_r[3]; l4i = pw_i[3];
        cmul(l8r, l8i, l4r, l4i, l4r, l4i);
        cmul(l16r, l16i, l8r, l8i, l8r, l8i);
        cmul(l32r, l32i, l16r, l16i, l16r, l16i);
        if (g == 0)      { lg_r = 1.f; lg_i = 0.f; }
        else if (g == 1) { lg_r = l4r; lg_i = l4i; }
        else if (g == 2) { lg_r = l8r; lg_i = l8i; }
        else             { cmul(lg_r, lg_i, l8r, l8i, l4r, l4i); }
    }

    float TCr = 0.f, TCi = 0.f;      // running tile carry (per wp group)

    const unsigned short* ub = ubf + (size_t)b * (LEN * HID);
    int srow32  = tid >> 4;          // 0..31
    int stg_src = srow32 * HID + ((((tid & 15) * 16) ^ ((srow32 & 7) << 4)) >> 1);

#define STAGE(buf, tt)                                                        \
    {                                                                         \
        const unsigned short* gs = ub + (size_t)(tt) * 16384 + stg_src;       \
        char* ls = &sU[buf][tid * 16];                                        \
        _Pragma("unroll")                                                     \
        for (int q = 0; q < 4; ++q)                                           \
            gload16(gs + q * 4096, ls + q * 8192);                            \
    }

    // ---- prologue: stage tile 0, drain ----
    STAGE(0, 0)
    __syncthreads();
    int cur = 0;

    for (int t = 0; t < 16; ++t) {
        int l0t = t * 128;

        if (t < 15) STAGE(cur ^ 1, t + 1)

        // ---- GEMM: wave rows wl*32..wl*32+31; B packs [re|im] ----
        const char* su = &sU[cur][0];
        f32x4 acc[2];
        acc[0] = (f32x4)(0.f); acc[1] = (f32x4)(0.f);
#pragma unroll
        for (int kc = 0; kc < 4; ++kc) {
#pragma unroll
            for (int mi = 0; mi < 2; ++mi) {
                int off = (wl * 32 + mi * 16 + fr) * 256 + ((kc * 64 + g * 16) ^ ((fr & 7) << 4));
                bf16x8 ah = *(const bf16x8*)(su + off);
                acc[mi] = __builtin_amdgcn_mfma_f32_16x16x32_bf16(ah, Bfh[kc], acc[mi], 0, 0, 0);
                acc[mi] = __builtin_amdgcn_mfma_f32_16x16x32_bf16(ah, Bfl[kc], acc[mi], 0, 0, 0);
            }
        }

        // ---- split swap: each lane keeps ONLY its own mi (= comp) ----
        float xr[4], xi[4];
#pragma unroll
        for (int e = 0; e < 4; ++e) {
            float send = (comp == 0) ? acc[1][e] : acc[0][e];
            float oth  = __shfl_xor(send, 8, 64);
            xr[e] = (comp == 0) ? acc[0][e] : oth;
            xi[e] = (comp == 0) ? oth       : acc[1][e];
        }

        // ---- scan phase 1 (split): quad scan + g-scan on own fragment ----
        float Er, Ei, Fr, Fi, For, Foi;
        {
            float lr = pw_r[0], li = pw_i[0];
            float cr = 0.f, ci = 0.f;
#pragma unroll
            for (int r = 0; r < 4; ++r) {
                float nr = fmaf(lr, cr, fmaf(-li, ci, xr[r]));
                float ni = fmaf(lr, ci, fmaf(li, cr, xi[r]));
                cr = nr; ci = ni;
                xr[r] = cr; xi[r] = ci;
            }
            float Qr = cr, Qi = ci;
            float ur = __shfl_up(Qr, 16u, 64);
            float ui = __shfl_up(Qi, 16u, 64);
            if (g >= 1) {
                Qr = fmaf(l4r, ur, fmaf(-l4i, ui, Qr));
                Qi = fmaf(l4r, ui, fmaf(l4i, ur, Qi));
            }
            ur = __shfl_up(Qr, 32u, 64);
            ui = __shfl_up(Qi, 32u, 64);
            if (g >= 2) {
                Qr = fmaf(l8r, ur, fmaf(-l8i, ui, Qr));
                Qi = fmaf(l8r, ui, fmaf(l8i, ur, Qi));
            }
            Er = __shfl_up(Qr, 16u, 64);
            Ei = __shfl_up(Qi, 16u, 64);
            if (g == 0) { Er = 0.f; Ei = 0.f; }
            Fr = __shfl(Qr, fr + 48, 64);   // own-frag total carry
            Fi = __shfl(Qi, fr + 48, 64);
            For = __shfl_xor(Fr, 8, 64);    // partner-frag carry
            Foi = __shfl_xor(Fi, 8, 64);
            float Rr = fmaf(l16r, For, fmaf(-l16i, Foi, Fr));
            float Ri = fmaf(l16r, Foi, fmaf(l16i, For, Fi));
            if (g == 0 && fr >= 8) { Rld[wl][wp][frp][0] = Rr; Rld[wl][wp][frp][1] = Ri; }
        }
        __syncthreads();   // bar2: Rld ready; sU[cur] reads done; staging drained

        // ---- scan phase 2: cross-wave lam^32 chain; own-mi corrections ----
        {
            float Wr = TCr, Wi = TCi;
            float Tr = TCr, Ti = TCi;
#pragma unroll
            for (int w2 = 0; w2 < 4; ++w2) {
                float rr = Rld[w2][wp][frp][0], ri = Rld[w2][wp][frp][1];
                float nTr = fmaf(l32r, Tr, fmaf(-l32i, Ti, rr));
                float nTi = fmaf(l32r, Ti, fmaf(l32i, Tr, ri));
                Tr = nTr; Ti = nTi;
                if (w2 < wl) {
                    float nWr = fmaf(l32r, Wr, fmaf(-l32i, Wi, rr));
                    float nWi = fmaf(l32r, Wi, fmaf(l32i, Wr, ri));
                    Wr = nWr; Wi = nWi;
                }
            }
            TCr = Tr; TCi = Ti;
            float prr, pri;
            if (comp == 0) { prr = Wr; pri = Wi; }
            else {
                prr = fmaf(l16r, Wr, fmaf(-l16i, Wi, For));
                pri = fmaf(l16r, Wi, fmaf(l16i, Wr, Foi));
            }
            float Mr = fmaf(lg_r, prr, fmaf(-lg_i, pri, Er));
            float Mi = fmaf(lg_r, pri, fmaf(lg_i, prr, Ei));
#pragma unroll
            for (int r = 0; r < 4; ++r) {
                xr[r] = fmaf(pw_r[r], Mr, fmaf(-pw_i[r], Mi, xr[r]));
                xi[r] = fmaf(pw_r[r], Mi, fmaf(pw_i[r], Mr, xi[r]));
            }
        }

        // ---- stage into sT2 [128 rows(l)][16 u32(kappa-pairs)+pad] ----
        {
            int colb  = wl * 32 + comp * 16 + g * 4;
            int idxu  = wp * 8 + frp;            // u32 index = local p
            int piece = idxu >> 2, sub = idxu & 3;
            int pw    = piece ^ g;               // swizzle key (row>>2)&3 == g
#pragma unroll
            for (int r = 0; r < 4; ++r) {
                unsigned int pk = cvtpk(xr[r], xi[r]);   // lo=re, hi=im
                *(unsigned int*)(sT2 + (colb + r) * 80 + pw * 16 + sub * 4) = pk;
            }
        }
        __syncthreads();   // bar3: sT2 ready

        // ---- stores: 128 rows x 64B contiguous into TP ----
        {
            int row = tid >> 2, q = tid & 3;
            int x2  = (row >> 2) & 3;
            bf16x8 v = *(const bf16x8*)(sT2 + row * 80 + ((q ^ x2) * 16));
            *(bf16x8*)&TP[((size_t)(b * LEN) + l0t + row) * 512 + p0 * 2 + q * 8] = v;
        }
        cur ^= 1;
    }
#undef STAGE
}

// ---------------------------------------------------------------------------
// K3 v3: flat real GEMM  out[b][l][h] = sum_{kappa} TP[b][l][k]*C2[..][h][k]
//        (+ u*D).  M=128 l, N=128 h (FULL — TP read exactly once), K=512 in
// 16 chunks of 32. 512-thread blocks (8 waves, wave tile 32l x 64h,
// 16 MFMA/chunk/wave). A+C staged via global_load_lds (source-folded XOR
// swizzle), double-buffered (48KB), 1 barrier/chunk. Grid 512, 2 blocks/CU.
// ---------------------------------------------------------------------------
__global__ __launch_bounds__(512, 4) void k3_out(const unsigned short* __restrict__ TP,
                                                 const unsigned short* __restrict__ C2,
                                                 const unsigned short* __restrict__ ubf,
                                                 const float* __restrict__ D,
                                                 float* __restrict__ out) {
    __shared__ __align__(16) char sAB[2][24576];  // A 8KB ([128 l][64B]) | C 16KB ([2 hilo][128 h][64B])

    int d    = blockIdx.x;            // 0..511
    int xcd  = d & 7;
    int rest = d >> 3;                // 0..63
    int lt   = rest & 15;
    int bhi  = rest >> 4;             // 0..3
    int b    = bhi * 8 + xcd;
    int l0   = lt * 128;

    int tid = threadIdx.x;
    int lane = tid & 63, w = tid >> 6;
    int wl = w >> 1, wh = w & 1;
    int fr = lane & 15, g = lane >> 4;

    f32x4 acc[2][4];
#pragma unroll
    for (int mi = 0; mi < 2; ++mi)
#pragma unroll
        for (int ni = 0; ni < 4; ++ni) acc[mi][ni] = (f32x4)(0.f);

    float dv[4];
#pragma unroll
    for (int ni = 0; ni < 4; ++ni) dv[ni] = D[wh * 64 + ni * 16 + fr];

#define STAGE3(buf, cc)                                                       \
    {                                                                         \
        /* A: 8KB = 512 thr x 16B */                                          \
        {                                                                     \
            int rw = tid >> 2, sl = tid & 3;                                  \
            gload16(TP + ((size_t)(b * LEN) + l0 + rw) * 512 + (cc) * 32 +    \
                        ((sl ^ (rw & 3)) * 8),                                \
                    &sAB[buf][tid * 16]);                                     \
        }                                                                     \
        /* C: 16KB = 512 thr x 2 x 16B */                                     \
        _Pragma("unroll")                                                     \
        for (int q = 0; q < 2; ++q) {                                         \
            int dg = tid + q * 512;                                           \
            int hl = dg >> 9, hr = (dg >> 2) & 127, sl = dg & 3;              \
            gload16(C2 + ((size_t)(hl * 128 + hr)) * 512 + (cc) * 32 +        \
                        ((sl ^ (hr & 3)) * 8),                                \
                    &sAB[buf][8192 + dg * 16]);                               \
        }                                                                     \
    }

    STAGE3(0, 0)
    __syncthreads();
    int cur = 0;

    for (int c = 0; c < 16; ++c) {
        if (c < 15) STAGE3(cur ^ 1, c + 1)

        const char* sb = &sAB[cur][0];
        int swz = (g ^ (fr & 3)) * 16;
        bf16x8 af[2];
#pragma unroll
        for (int mi = 0; mi < 2; ++mi) {
            int arow = wl * 32 + mi * 16 + fr;
            af[mi] = *(const bf16x8*)(sb + arow * 64 + swz);
        }
#pragma unroll
        for (int ni = 0; ni < 4; ++ni) {
            int hrow = wh * 64 + ni * 16 + fr;
            bf16x8 ch = *(const bf16x8*)(sb + 8192 + hrow * 64 + swz);
            bf16x8 cl = *(const bf16x8*)(sb + 8192 + 8192 + hrow * 64 + swz);
#pragma unroll
            for (int mi = 0; mi < 2; ++mi) {
                acc[mi][ni] = __builtin_amdgcn_mfma_f32_16x16x32_bf16(af[mi], ch, acc[mi][ni], 0, 0, 0);
                acc[mi][ni] = __builtin_amdgcn_mfma_f32_16x16x32_bf16(af[mi], cl, acc[mi][ni], 0, 0, 0);
            }
        }
        __syncthreads();
        cur ^= 1;
    }
#undef STAGE3

#pragma unroll
    for (int mi = 0; mi < 2; ++mi)
#pragma unroll
        for (int ni = 0; ni < 4; ++ni) {
            int lb = l0 + wl * 32 + mi * 16 + g * 4;
            int h  = wh * 64 + ni * 16 + fr;
#pragma unroll
            for (int r = 0; r < 4; ++r) {
                size_t idx = ((size_t)b * LEN + lb + r) * HID + h;
                out[idx] = acc[mi][ni][r] + bf2f(ubf[idx]) * dv[ni];
            }
        }
}

// ---------------------------------------------------------------------------
// Workspace layout (bytes):
//   [0, 67108864)              TP: states, kappa-interleaved [b][l][512]
//   [67108864, 67110912)       lam (512 f32)
//   [67110912, 67373056)       B split planes (4 x 32768 ushort)
//   [67373056, 67635200)       C2 (2 hilo x 128 h x 512 kappa ushort)
//   [67635200, 84412416)       ubf: u as bf16 [b][l][h]
// ---------------------------------------------------------------------------
extern "C" void kernel_launch(void* const* d_in, const int* in_sizes, int n_in,
                              void* d_out, int out_size, void* d_ws, size_t ws_size,
                              hipStream_t stream) {
    const float* u  = (const float*)d_in[0];
    const float* A  = (const float*)d_in[1];
    const float* G  = (const float*)d_in[2];
    const float* st = (const float*)d_in[3];
    const float* B  = (const float*)d_in[4];
    const float* C  = (const float*)d_in[5];
    const float* D  = (const float*)d_in[6];
    float* out = (float*)d_out;

    char* WS = (char*)d_ws;
    unsigned short* TP  = (unsigned short*)WS;
    float* lam          = (float*)(WS + 67108864);
    unsigned short* Bsp = (unsigned short*)(WS + 67110912);
    unsigned short* C2  = (unsigned short*)(WS + 67373056);
    unsigned short* ubf = (unsigned short*)(WS + 67635200);

    k0b_prep<<<257, 256, 0, stream>>>(B, C, A, G, st, Bsp, C2, lam);
    ku_cvt<<<2048, 256, 0, stream>>>(u, ubf);
    k12_fused<<<512, 512, 0, stream>>>(ubf, Bsp, lam, TP);
    k3_out<<<512, 512, 0, stream>>>(TP, C2, ubf, D, out);
}

// Round 15
// 81.712 us; speedup vs baseline: 1.1117x; 1.0578x over previous
//
#include <hip/hip_runtime.h>
#include <hip/hip_bf16.h>
#include <math.h>

#define BATCH 32
#define LEN   2048
#define HID   128
#define SSM   256

#define BPL 32768                     // elements per B-split plane (256*128)

typedef __attribute__((ext_vector_type(4))) float f32x4;
typedef __attribute__((ext_vector_type(8))) short bf16x8;
typedef __attribute__((ext_vector_type(4))) int   i32x4;

// RNE f32->bf16 (bit trick)
static __device__ __forceinline__ unsigned short f2bf(float x) {
    union { float f; unsigned u; } v; v.f = x;
    unsigned r = (v.u + 0x7FFFu + ((v.u >> 16) & 1u)) >> 16;
    return (unsigned short)r;
}
// truncating f32->bf16 (hi term of split; lo captures remainder exactly)
static __device__ __forceinline__ unsigned short f2bf_hi(float x) {
    union { float f; unsigned u; } v; v.f = x;
    return (unsigned short)(v.u >> 16);
}
static __device__ __forceinline__ float bf2f(unsigned short b) {
    union { unsigned u; float f; } v; v.u = ((unsigned)b) << 16;
    return v.f;
}
// packed RNE pair convert -> one u32 (v_cvt_pk_bf16_f32); lo half = first arg
static __device__ __forceinline__ unsigned int cvtpk(float a, float b) {
    __hip_bfloat162 h = __float22bfloat162_rn(float2{a, b});
    union { __hip_bfloat162 h2; unsigned int u; } c; c.h2 = h;
    return c.u;
}
static __device__ __forceinline__ void cmul(float& rr, float& ri,
                                            float ar, float ai, float br, float bi) {
    rr = ar * br - ai * bi;
    ri = ar * bi + ai * br;
}
// async global->LDS 16B (zero VGPR round-trip; vmcnt-counted)
static __device__ __forceinline__ void gload16(const void* g, void* l) {
    __builtin_amdgcn_global_load_lds(
        (const __attribute__((address_space(1))) unsigned int*)g,
        (__attribute__((address_space(3))) unsigned int*)l,
        16, 0, 0);
}

// ---------------------------------------------------------------------------
// KPREP (merged): blocks 0..2047 stream-convert u->ubf; blocks 2048..2303
// pre-split B (hi/lo, [p][h]) and C2 (kappa-interleaved, im NEGATED);
// block 2304 computes lam.
// ---------------------------------------------------------------------------
__global__ __launch_bounds__(256) void kprep(const float* __restrict__ u,
                                             const float* __restrict__ Bm,
                                             const float* __restrict__ Cm,
                                             const float* __restrict__ A,
                                             const float* __restrict__ G,
                                             const float* __restrict__ steps,
                                             unsigned short* __restrict__ ubf,
                                             unsigned short* __restrict__ Bsp,
                                             unsigned short* __restrict__ C2,
                                             float* __restrict__ lam) {
    if (blockIdx.x < 2048) {
        const int total = BATCH * LEN * HID;
        const int stride = 2048 * 256 * 8;
        for (int i = (blockIdx.x * 256 + threadIdx.x) * 8; i < total; i += stride) {
            f32x4 a = *(const f32x4*)&u[i];
            f32x4 c = *(const f32x4*)&u[i + 4];
            i32x4 o;
            o[0] = (int)cvtpk(a[0], a[1]);
            o[1] = (int)cvtpk(a[2], a[3]);
            o[2] = (int)cvtpk(c[0], c[1]);
            o[3] = (int)cvtpk(c[2], c[3]);
            *(i32x4*)&ubf[i] = o;
        }
        return;
    }
    if (blockIdx.x == 2304) {
        int p = threadIdx.x;
        if (p < SSM) {
            float stp   = 1.f / (1.f + expf(-steps[p]));
            float g     = fmaxf(G[p], 0.f);
            float denom = fmaxf(stp * stp, 1e-6f);
            float s     = stp * g;
            float base  = sqrtf(fmaxf(1.f + s, 1e-6f));
            float alow  = (2.f + s - 2.f * base) / denom;
            float ahigh = (2.f + s + 2.f * base) / denom;
            float a     = alow + fmaxf(A[p] - alow, 0.f) - fmaxf(A[p] - ahigh, 0.f);
            float S     = 1.f / (1.f + stp * g);
            float T     = S + 1.f - stp * stp * S * a;
            lam[p]       = 0.5f * T;
            lam[SSM + p] = sqrtf(fmaxf(S - 0.25f * T * T, 0.f));
        }
        return;
    }
    int gidx = (blockIdx.x - 2048) * 256 + threadIdx.x;
    if (gidx < 32768) {
        int p = gidx >> 7, h = gidx & 127;
        float vr = Bm[(size_t)(p * HID + h) * 2];
        float vi = Bm[(size_t)(p * HID + h) * 2 + 1];
        unsigned short hh = f2bf_hi(vr);
        Bsp[0 * BPL + p * HID + h] = hh;
        Bsp[1 * BPL + p * HID + h] = f2bf(vr - bf2f(hh));
        hh = f2bf_hi(vi);
        Bsp[2 * BPL + p * HID + h] = hh;
        Bsp[3 * BPL + p * HID + h] = f2bf(vi - bf2f(hh));
    } else {
        int g2 = gidx - 32768;
        int h = g2 >> 8, p = g2 & 255;
        float vr = Cm[(size_t)(h * SSM + p) * 2];
        float vi = -Cm[(size_t)(h * SSM + p) * 2 + 1];
        unsigned short rh = f2bf_hi(vr);
        unsigned short ih = f2bf_hi(vi);
        size_t rowh = (size_t)h * 512;
        C2[rowh + 2 * p]               = rh;
        C2[rowh + 2 * p + 1]           = ih;
        C2[65536 + rowh + 2 * p]       = f2bf(vr - bf2f(rh));
        C2[65536 + rowh + 2 * p + 1]   = f2bf(vi - bf2f(ih));
    }
}

// ---------------------------------------------------------------------------
// K12 v11: R13/R14-verified split-scan kernel; ONLY change: bar2 is now a
// raw s_barrier with lgkmcnt(0)-only wait (Rld publish + sU ds_read retire
// need only LGKM). The vmcnt drain of STAGE(t+1) stays at bar3
// (__syncthreads), giving staged loads the full GEMM+ph1+ph2+sT2 span (T4).
// ---------------------------------------------------------------------------
__global__ __launch_bounds__(512, 4) void k12_fused(const unsigned short* __restrict__ ubf,
                                                    const unsigned short* __restrict__ Bsp,
                                                    const float* __restrict__ lam,
                                                    unsigned short* __restrict__ TP) {
    __shared__ __align__(16) char sU[2][32768];   // dbuf: 128 rows x 256B
    __shared__ __align__(16) char sT2[10240];     // 128 rows x 80B (64 data + pad)
    __shared__ float Rld[4][2][8][2];             // [wl][wp][p8][re/im]

    int d    = blockIdx.x;           // 0..511
    int xcd  = d & 7;
    int idx  = d >> 3;               // 0..63
    int pt   = idx & 15;             // 16 p-tiles of 16
    int bhi  = idx >> 4;             // 0..3
    int b    = bhi * 8 + xcd;
    int p0   = pt * 16;

    int tid  = threadIdx.x;
    int lane = tid & 63, w = tid >> 6;
    int wl   = w >> 1, wp = w & 1;
    int fr   = lane & 15, g = lane >> 4;
    int frp  = fr & 7;               // p-column within octet
    int comp = fr >> 3;              // 0 = re-half (owns mi=0), 1 = im-half (owns mi=1)
    int pcol = p0 + wp * 8 + frp;    // this lane's p

    // ---- B fragments: lane's comp & p-col, hi/lo x 4 k-chunks ----
    const unsigned short* Bh  = Bsp + (size_t)(comp * 2) * BPL + (size_t)pcol * HID;
    const unsigned short* Blo = Bsp + (size_t)(comp * 2 + 1) * BPL + (size_t)pcol * HID;
    bf16x8 Bfh[4], Bfl[4];
#pragma unroll
    for (int kc = 0; kc < 4; ++kc) {
        Bfh[kc] = *(const bf16x8*)&Bh[kc * 32 + g * 8];
        Bfl[kc] = *(const bf16x8*)&Blo[kc * 32 + g * 8];
    }

    // ---- lambda powers for p = pcol ----
    float pw_r[4], pw_i[4];          // lam^(r+1)
    float lg_r, lg_i;                // lam^(4g)
    float l4r, l4i, l8r, l8i, l16r, l16i, l32r, l32i;
    {
        float ar = lam[pcol], ai = lam[SSM + pcol];
        pw_r[0] = ar; pw_i[0] = ai;
        cmul(pw_r[1], pw_i[1], ar, ai, ar, ai);
        cmul(pw_r[2], pw_i[2], pw_r[1], pw_i[1], ar, ai);
        cmul(pw_r[3], pw_i[3], pw_r[1], pw_i[1], pw_r[1], pw_i[1]);
        l4r = pw_r[3]; l4i = pw_i[3];
        cmul(l8r, l8i, l4r, l4i, l4r, l4i);
        cmul(l16r, l16i, l8r, l8i, l8r, l8i);
        cmul(l32r, l32i, l16r, l16i, l16r, l16i);
        if (g == 0)      { lg_r = 1.f; lg_i = 0.f; }
        else if (g == 1) { lg_r = l4r; lg_i = l4i; }
        else if (g == 2) { lg_r = l8r; lg_i = l8i; }
        else             { cmul(lg_r, lg_i, l8r, l8i, l4r, l4i); }
    }

    float TCr = 0.f, TCi = 0.f;      // running tile carry (per wp group)

    const unsigned short* ub = ubf + (size_t)b * (LEN * HID);
    int srow32  = tid >> 4;          // 0..31
    int stg_src = srow32 * HID + ((((tid & 15) * 16) ^ ((srow32 & 7) << 4)) >> 1);

#define STAGE(buf, tt)                                                        \
    {                                                                         \
        const unsigned short* gs = ub + (size_t)(tt) * 16384 + stg_src;       \
        char* ls = &sU[buf][tid * 16];                                        \
        _Pragma("unroll")                                                     \
        for (int q = 0; q < 4; ++q)                                           \
            gload16(gs + q * 4096, ls + q * 8192);                            \
    }

    // ---- prologue: stage tile 0, drain ----
    STAGE(0, 0)
    __syncthreads();
    int cur = 0;

    for (int t = 0; t < 16; ++t) {
        int l0t = t * 128;

        if (t < 15) STAGE(cur ^ 1, t + 1)

        // ---- GEMM: wave rows wl*32..wl*32+31; B packs [re|im] ----
        const char* su = &sU[cur][0];
        f32x4 acc[2];
        acc[0] = (f32x4)(0.f); acc[1] = (f32x4)(0.f);
#pragma unroll
        for (int kc = 0; kc < 4; ++kc) {
#pragma unroll
            for (int mi = 0; mi < 2; ++mi) {
                int off = (wl * 32 + mi * 16 + fr) * 256 + ((kc * 64 + g * 16) ^ ((fr & 7) << 4));
                bf16x8 ah = *(const bf16x8*)(su + off);
                acc[mi] = __builtin_amdgcn_mfma_f32_16x16x32_bf16(ah, Bfh[kc], acc[mi], 0, 0, 0);
                acc[mi] = __builtin_amdgcn_mfma_f32_16x16x32_bf16(ah, Bfl[kc], acc[mi], 0, 0, 0);
            }
        }

        // ---- split swap: each lane keeps ONLY its own mi (= comp) ----
        float xr[4], xi[4];
#pragma unroll
        for (int e = 0; e < 4; ++e) {
            float send = (comp == 0) ? acc[1][e] : acc[0][e];
            float oth  = __shfl_xor(send, 8, 64);
            xr[e] = (comp == 0) ? acc[0][e] : oth;
            xi[e] = (comp == 0) ? oth       : acc[1][e];
        }

        // ---- scan phase 1 (split): quad scan + g-scan on own fragment ----
        float Er, Ei, Fr, Fi, For, Foi;
        {
            float lr = pw_r[0], li = pw_i[0];
            float cr = 0.f, ci = 0.f;
#pragma unroll
            for (int r = 0; r < 4; ++r) {
                float nr = fmaf(lr, cr, fmaf(-li, ci, xr[r]));
                float ni = fmaf(lr, ci, fmaf(li, cr, xi[r]));
                cr = nr; ci = ni;
                xr[r] = cr; xi[r] = ci;
            }
            float Qr = cr, Qi = ci;
            float ur = __shfl_up(Qr, 16u, 64);
            float ui = __shfl_up(Qi, 16u, 64);
            if (g >= 1) {
                Qr = fmaf(l4r, ur, fmaf(-l4i, ui, Qr));
                Qi = fmaf(l4r, ui, fmaf(l4i, ur, Qi));
            }
            ur = __shfl_up(Qr, 32u, 64);
            ui = __shfl_up(Qi, 32u, 64);
            if (g >= 2) {
                Qr = fmaf(l8r, ur, fmaf(-l8i, ui, Qr));
                Qi = fmaf(l8r, ui, fmaf(l8i, ur, Qi));
            }
            Er = __shfl_up(Qr, 16u, 64);
            Ei = __shfl_up(Qi, 16u, 64);
            if (g == 0) { Er = 0.f; Ei = 0.f; }
            Fr = __shfl(Qr, fr + 48, 64);   // own-frag total carry
            Fi = __shfl(Qi, fr + 48, 64);
            For = __shfl_xor(Fr, 8, 64);    // partner-frag carry
            Foi = __shfl_xor(Fi, 8, 64);
            float Rr = fmaf(l16r, For, fmaf(-l16i, Foi, Fr));
            float Ri = fmaf(l16r, Foi, fmaf(l16i, For, Fi));
            if (g == 0 && fr >= 8) { Rld[wl][wp][frp][0] = Rr; Rld[wl][wp][frp][1] = Ri; }
        }
        // ---- bar2 (raw): LGKM-only — do NOT drain the staged vmcnt loads ----
        asm volatile("s_waitcnt lgkmcnt(0)" ::: "memory");
        __builtin_amdgcn_s_barrier();
        __builtin_amdgcn_sched_barrier(0);

        // ---- scan phase 2: cross-wave lam^32 chain; own-mi corrections ----
        {
            float Wr = TCr, Wi = TCi;
            float Tr = TCr, Ti = TCi;
#pragma unroll
            for (int w2 = 0; w2 < 4; ++w2) {
                float rr = Rld[w2][wp][frp][0], ri = Rld[w2][wp][frp][1];
                float nTr = fmaf(l32r, Tr, fmaf(-l32i, Ti, rr));
                float nTi = fmaf(l32r, Ti, fmaf(l32i, Tr, ri));
                Tr = nTr; Ti = nTi;
                if (w2 < wl) {
                    float nWr = fmaf(l32r, Wr, fmaf(-l32i, Wi, rr));
                    float nWi = fmaf(l32r, Wi, fmaf(l32i, Wr, ri));
                    Wr = nWr; Wi = nWi;
                }
            }
            TCr = Tr; TCi = Ti;
            float prr, pri;
            if (comp == 0) { prr = Wr; pri = Wi; }
            else {
                prr = fmaf(l16r, Wr, fmaf(-l16i, Wi, For));
                pri = fmaf(l16r, Wi, fmaf(l16i, Wr, Foi));
            }
            float Mr = fmaf(lg_r, prr, fmaf(-lg_i, pri, Er));
            float Mi = fmaf(lg_r, pri, fmaf(lg_i, prr, Ei));
#pragma unroll
            for (int r = 0; r < 4; ++r) {
                xr[r] = fmaf(pw_r[r], Mr, fmaf(-pw_i[r], Mi, xr[r]));
                xi[r] = fmaf(pw_r[r], Mi, fmaf(pw_i[r], Mr, xi[r]));
            }
        }

        // ---- stage into sT2 [128 rows(l)][16 u32(kappa-pairs)+pad] ----
        {
            int colb  = wl * 32 + comp * 16 + g * 4;
            int idxu  = wp * 8 + frp;            // u32 index = local p
            int piece = idxu >> 2, sub = idxu & 3;
            int pw    = piece ^ g;               // swizzle key (row>>2)&3 == g
#pragma unroll
            for (int r = 0; r < 4; ++r) {
                unsigned int pk = cvtpk(xr[r], xi[r]);   // lo=re, hi=im
                *(unsigned int*)(sT2 + (colb + r) * 80 + pw * 16 + sub * 4) = pk;
            }
        }
        __syncthreads();   // bar3: sT2 ready + staged loads (vmcnt) drained

        // ---- stores: 128 rows x 64B contiguous into TP ----
        {
            int row = tid >> 2, q = tid & 3;
            int x2  = (row >> 2) & 3;
            bf16x8 v = *(const bf16x8*)(sT2 + row * 80 + ((q ^ x2) * 16));
            *(bf16x8*)&TP[((size_t)(b * LEN) + l0t + row) * 512 + p0 * 2 + q * 8] = v;
        }
        cur ^= 1;
    }
#undef STAGE
}

// ---------------------------------------------------------------------------
// K3 v4: R14's verified flat GEMM re-piped to 3 buffers, depth-2 staging,
// counted vmcnt(3) at a raw barrier (3 gload16/thread per chunk; newest 3
// are the just-issued c+2 stage). Tail chunks (no new stage in flight)
// drain fully. Math/tiling byte-identical to R14 k3-v3.
// ---------------------------------------------------------------------------
__global__ __launch_bounds__(512, 4) void k3_out(const unsigned short* __restrict__ TP,
                                                 const unsigned short* __restrict__ C2,
                                                 const unsigned short* __restrict__ ubf,
                                                 const float* __restrict__ D,
                                                 float* __restrict__ out) {
    __shared__ __align__(16) char sAB[3][24576];  // A 8KB ([128 l][64B]) | C 16KB ([2 hilo][128 h][64B])

    int d    = blockIdx.x;            // 0..511
    int xcd  = d & 7;
    int rest = d >> 3;                // 0..63
    int lt   = rest & 15;
    int bhi  = rest >> 4;             // 0..3
    int b    = bhi * 8 + xcd;
    int l0   = lt * 128;

    int tid = threadIdx.x;
    int lane = tid & 63, w = tid >> 6;
    int wl = w >> 1, wh = w & 1;
    int fr = lane & 15, g = lane >> 4;

    f32x4 acc[2][4];
#pragma unroll
    for (int mi = 0; mi < 2; ++mi)
#pragma unroll
        for (int ni = 0; ni < 4; ++ni) acc[mi][ni] = (f32x4)(0.f);

    float dv[4];
#pragma unroll
    for (int ni = 0; ni < 4; ++ni) dv[ni] = D[wh * 64 + ni * 16 + fr];

#define STAGE3(buf, cc)                                                       \
    {                                                                         \
        {                                                                     \
            int rw = tid >> 2, sl = tid & 3;                                  \
            gload16(TP + ((size_t)(b * LEN) + l0 + rw) * 512 + (cc) * 32 +    \
                        ((sl ^ (rw & 3)) * 8),                                \
                    &sAB[buf][tid * 16]);                                     \
        }                                                                     \
        _Pragma("unroll")                                                     \
        for (int q = 0; q < 2; ++q) {                                         \
            int dg = tid + q * 512;                                           \
            int hl = dg >> 9, hr = (dg >> 2) & 127, sl = dg & 3;              \
            gload16(C2 + ((size_t)(hl * 128 + hr)) * 512 + (cc) * 32 +        \
                        ((sl ^ (hr & 3)) * 8),                                \
                    &sAB[buf][8192 + dg * 16]);                               \
        }                                                                     \
    }

    STAGE3(0, 0)
    __syncthreads();
    STAGE3(1, 1)

    int cur = 0;
    for (int c = 0; c < 16; ++c) {
        if (c < 14) STAGE3((cur + 2) % 3, c + 2)

        const char* sb = &sAB[cur][0];
        int swz = (g ^ (fr & 3)) * 16;
        bf16x8 af[2];
#pragma unroll
        for (int mi = 0; mi < 2; ++mi) {
            int arow = wl * 32 + mi * 16 + fr;
            af[mi] = *(const bf16x8*)(sb + arow * 64 + swz);
        }
#pragma unroll
        for (int ni = 0; ni < 4; ++ni) {
            int hrow = wh * 64 + ni * 16 + fr;
            bf16x8 ch = *(const bf16x8*)(sb + 8192 + hrow * 64 + swz);
            bf16x8 cl = *(const bf16x8*)(sb + 8192 + 8192 + hrow * 64 + swz);
#pragma unroll
            for (int mi = 0; mi < 2; ++mi) {
                acc[mi][ni] = __builtin_amdgcn_mfma_f32_16x16x32_bf16(af[mi], ch, acc[mi][ni], 0, 0, 0);
                acc[mi][ni] = __builtin_amdgcn_mfma_f32_16x16x32_bf16(af[mi], cl, acc[mi][ni], 0, 0, 0);
            }
        }
        // raw barrier: wait for the (c+1) stage only — newest 3 loads (the
        // c+2 stage) may stay in flight. Tail: nothing new issued -> drain.
        if (c < 14) {
            asm volatile("s_waitcnt vmcnt(3) lgkmcnt(0)" ::: "memory");
        } else {
            asm volatile("s_waitcnt vmcnt(0) lgkmcnt(0)" ::: "memory");
        }
        __builtin_amdgcn_s_barrier();
        __builtin_amdgcn_sched_barrier(0);
        cur = (cur + 1) % 3;
    }
#undef STAGE3

#pragma unroll
    for (int mi = 0; mi < 2; ++mi)
#pragma unroll
        for (int ni = 0; ni < 4; ++ni) {
            int lb = l0 + wl * 32 + mi * 16 + g * 4;
            int h  = wh * 64 + ni * 16 + fr;
#pragma unroll
            for (int r = 0; r < 4; ++r) {
                size_t idx = ((size_t)b * LEN + lb + r) * HID + h;
                out[idx] = acc[mi][ni][r] + bf2f(ubf[idx]) * dv[ni];
            }
        }
}

// ---------------------------------------------------------------------------
// Workspace layout (bytes):
//   [0, 67108864)              TP: states, kappa-interleaved [b][l][512]
//   [67108864, 67110912)       lam (512 f32)
//   [67110912, 67373056)       B split planes (4 x 32768 ushort)
//   [67373056, 67635200)       C2 (2 hilo x 128 h x 512 kappa ushort)
//   [67635200, 84412416)       ubf: u as bf16 [b][l][h]
// ---------------------------------------------------------------------------
extern "C" void kernel_launch(void* const* d_in, const int* in_sizes, int n_in,
                              void* d_out, int out_size, void* d_ws, size_t ws_size,
                              hipStream_t stream) {
    const float* u  = (const float*)d_in[0];
    const float* A  = (const float*)d_in[1];
    const float* G  = (const float*)d_in[2];
    const float* st = (const float*)d_in[3];
    const float* B  = (const float*)d_in[4];
    const float* C  = (const float*)d_in[5];
    const float* D  = (const float*)d_in[6];
    float* out = (float*)d_out;

    char* WS = (char*)d_ws;
    unsigned short* TP  = (unsigned short*)WS;
    float* lam          = (float*)(WS + 67108864);
    unsigned short* Bsp = (unsigned short*)(WS + 67110912);
    unsigned short* C2  = (unsigned short*)(WS + 67373056);
    unsigned short* ubf = (unsigned short*)(WS + 67635200);

    kprep<<<2305, 256, 0, stream>>>(u, B, C, A, G, st, ubf, Bsp, C2, lam);
    k12_fused<<<512, 512, 0, stream>>>(ubf, Bsp, lam, TP);
    k3_out<<<512, 512, 0, stream>>>(TP, C2, ubf, D, out);
}

// Round 16
// 79.311 us; speedup vs baseline: 1.1453x; 1.0303x over previous
//
#include <hip/hip_runtime.h>
#include <hip/hip_bf16.h>
#include <math.h>

#define BATCH 32
#define LEN   2048
#define HID   128
#define SSM   256

#define BPL 32768                     // elements per B-split plane (256*128)

typedef __attribute__((ext_vector_type(4))) float f32x4;
typedef __attribute__((ext_vector_type(8))) short bf16x8;
typedef __attribute__((ext_vector_type(4))) int   i32x4;

// RNE f32->bf16 (bit trick)
static __device__ __forceinline__ unsigned short f2bf(float x) {
    union { float f; unsigned u; } v; v.f = x;
    unsigned r = (v.u + 0x7FFFu + ((v.u >> 16) & 1u)) >> 16;
    return (unsigned short)r;
}
// truncating f32->bf16 (hi term of split; lo captures remainder exactly)
static __device__ __forceinline__ unsigned short f2bf_hi(float x) {
    union { float f; unsigned u; } v; v.f = x;
    return (unsigned short)(v.u >> 16);
}
static __device__ __forceinline__ float bf2f(unsigned short b) {
    union { unsigned u; float f; } v; v.u = ((unsigned)b) << 16;
    return v.f;
}
// packed RNE pair convert -> one u32 (v_cvt_pk_bf16_f32); lo half = first arg
static __device__ __forceinline__ unsigned int cvtpk(float a, float b) {
    __hip_bfloat162 h = __float22bfloat162_rn(float2{a, b});
    union { __hip_bfloat162 h2; unsigned int u; } c; c.h2 = h;
    return c.u;
}
static __device__ __forceinline__ void cmul(float& rr, float& ri,
                                            float ar, float ai, float br, float bi) {
    rr = ar * br - ai * bi;
    ri = ar * bi + ai * br;
}
// async global->LDS 16B (zero VGPR round-trip; vmcnt-counted)
static __device__ __forceinline__ void gload16(const void* g, void* l) {
    __builtin_amdgcn_global_load_lds(
        (const __attribute__((address_space(1))) unsigned int*)g,
        (__attribute__((address_space(3))) unsigned int*)l,
        16, 0, 0);
}

// ---------------------------------------------------------------------------
// KPREP (merged): blocks 0..2047 stream-convert u->ubf; blocks 2048..2303
// pre-split B (hi/lo, [p][h]) and C2 (kappa-interleaved, im NEGATED);
// block 2304 computes lam.   (verified R15)
// ---------------------------------------------------------------------------
__global__ __launch_bounds__(256) void kprep(const float* __restrict__ u,
                                             const float* __restrict__ Bm,
                                             const float* __restrict__ Cm,
                                             const float* __restrict__ A,
                                             const float* __restrict__ G,
                                             const float* __restrict__ steps,
                                             unsigned short* __restrict__ ubf,
                                             unsigned short* __restrict__ Bsp,
                                             unsigned short* __restrict__ C2,
                                             float* __restrict__ lam) {
    if (blockIdx.x < 2048) {
        const int total = BATCH * LEN * HID;
        const int stride = 2048 * 256 * 8;
        for (int i = (blockIdx.x * 256 + threadIdx.x) * 8; i < total; i += stride) {
            f32x4 a = *(const f32x4*)&u[i];
            f32x4 c = *(const f32x4*)&u[i + 4];
            i32x4 o;
            o[0] = (int)cvtpk(a[0], a[1]);
            o[1] = (int)cvtpk(a[2], a[3]);
            o[2] = (int)cvtpk(c[0], c[1]);
            o[3] = (int)cvtpk(c[2], c[3]);
            *(i32x4*)&ubf[i] = o;
        }
        return;
    }
    if (blockIdx.x == 2304) {
        int p = threadIdx.x;
        if (p < SSM) {
            float stp   = 1.f / (1.f + expf(-steps[p]));
            float g     = fmaxf(G[p], 0.f);
            float denom = fmaxf(stp * stp, 1e-6f);
            float s     = stp * g;
            float base  = sqrtf(fmaxf(1.f + s, 1e-6f));
            float alow  = (2.f + s - 2.f * base) / denom;
            float ahigh = (2.f + s + 2.f * base) / denom;
            float a     = alow + fmaxf(A[p] - alow, 0.f) - fmaxf(A[p] - ahigh, 0.f);
            float S     = 1.f / (1.f + stp * g);
            float T     = S + 1.f - stp * stp * S * a;
            lam[p]       = 0.5f * T;
            lam[SSM + p] = sqrtf(fmaxf(S - 0.25f * T * T, 0.f));
        }
        return;
    }
    int gidx = (blockIdx.x - 2048) * 256 + threadIdx.x;
    if (gidx < 32768) {
        int p = gidx >> 7, h = gidx & 127;
        float vr = Bm[(size_t)(p * HID + h) * 2];
        float vi = Bm[(size_t)(p * HID + h) * 2 + 1];
        unsigned short hh = f2bf_hi(vr);
        Bsp[0 * BPL + p * HID + h] = hh;
        Bsp[1 * BPL + p * HID + h] = f2bf(vr - bf2f(hh));
        hh = f2bf_hi(vi);
        Bsp[2 * BPL + p * HID + h] = hh;
        Bsp[3 * BPL + p * HID + h] = f2bf(vi - bf2f(hh));
    } else {
        int g2 = gidx - 32768;
        int h = g2 >> 8, p = g2 & 255;
        float vr = Cm[(size_t)(h * SSM + p) * 2];
        float vi = -Cm[(size_t)(h * SSM + p) * 2 + 1];
        unsigned short rh = f2bf_hi(vr);
        unsigned short ih = f2bf_hi(vi);
        size_t rowh = (size_t)h * 512;
        C2[rowh + 2 * p]               = rh;
        C2[rowh + 2 * p + 1]           = ih;
        C2[65536 + rowh + 2 * p]       = f2bf(vr - bf2f(rh));
        C2[65536 + rowh + 2 * p + 1]   = f2bf(vi - bf2f(ih));
    }
}

// ---------------------------------------------------------------------------
// K12 v12: verified R13-R15 split-scan core, restructured to ONE barrier per
// tile: sT2 transpose staging DELETED — after ph2 each lane stores its 4
// (re,im) pairs DIRECTLY to the kappa-interleaved TP as aligned u32s
// (8 lanes = 32B contiguous). Rld double-buffered (t&1) so ph1(t+1) cannot
// race ph2(t). The single __syncthreads per tile publishes Rld (lgkm),
// drains STAGE(t+1) (vmcnt), and retires sU[cur] reads. MFMA accumulation
// split into 2 independent 4-chains per mi (shorter critical path; ~ulp
// fp reorder).
// ---------------------------------------------------------------------------
__global__ __launch_bounds__(512, 4) void k12_fused(const unsigned short* __restrict__ ubf,
                                                    const unsigned short* __restrict__ Bsp,
                                                    const float* __restrict__ lam,
                                                    unsigned short* __restrict__ TP) {
    __shared__ __align__(16) char sU[2][32768];   // dbuf: 128 rows x 256B
    __shared__ float Rld[2][4][2][8][2];          // [t&1][wl][wp][p8][re/im]

    int d    = blockIdx.x;           // 0..511
    int xcd  = d & 7;
    int idx  = d >> 3;               // 0..63
    int pt   = idx & 15;             // 16 p-tiles of 16
    int bhi  = idx >> 4;             // 0..3
    int b    = bhi * 8 + xcd;
    int p0   = pt * 16;

    int tid  = threadIdx.x;
    int lane = tid & 63, w = tid >> 6;
    int wl   = w >> 1, wp = w & 1;
    int fr   = lane & 15, g = lane >> 4;
    int frp  = fr & 7;               // p-column within octet
    int comp = fr >> 3;              // 0 = re-half (owns mi=0), 1 = im-half (owns mi=1)
    int pcol = p0 + wp * 8 + frp;    // this lane's p

    // ---- B fragments: lane's comp & p-col, hi/lo x 4 k-chunks ----
    const unsigned short* Bh  = Bsp + (size_t)(comp * 2) * BPL + (size_t)pcol * HID;
    const unsigned short* Blo = Bsp + (size_t)(comp * 2 + 1) * BPL + (size_t)pcol * HID;
    bf16x8 Bfh[4], Bfl[4];
#pragma unroll
    for (int kc = 0; kc < 4; ++kc) {
        Bfh[kc] = *(const bf16x8*)&Bh[kc * 32 + g * 8];
        Bfl[kc] = *(const bf16x8*)&Blo[kc * 32 + g * 8];
    }

    // ---- lambda powers for p = pcol ----
    float pw_r[4], pw_i[4];          // lam^(r+1)
    float lg_r, lg_i;                // lam^(4g)
    float l4r, l4i, l8r, l8i, l16r, l16i, l32r, l32i;
    {
        float ar = lam[pcol], ai = lam[SSM + pcol];
        pw_r[0] = ar; pw_i[0] = ai;
        cmul(pw_r[1], pw_i[1], ar, ai, ar, ai);
        cmul(pw_r[2], pw_i[2], pw_r[1], pw_i[1], ar, ai);
        cmul(pw_r[3], pw_i[3], pw_r[1], pw_i[1], pw_r[1], pw_i[1]);
        l4r = pw_r[3]; l4i = pw_i[3];
        cmul(l8r, l8i, l4r, l4i, l4r, l4i);
        cmul(l16r, l16i, l8r, l8i, l8r, l8i);
        cmul(l32r, l32i, l16r, l16i, l16r, l16i);
        if (g == 0)      { lg_r = 1.f; lg_i = 0.f; }
        else if (g == 1) { lg_r = l4r; lg_i = l4i; }
        else if (g == 2) { lg_r = l8r; lg_i = l8i; }
        else             { cmul(lg_r, lg_i, l8r, l8i, l4r, l4i); }
    }

    float TCr = 0.f, TCi = 0.f;      // running tile carry (per wp group)

    const unsigned short* ub = ubf + (size_t)b * (LEN * HID);
    int srow32  = tid >> 4;          // 0..31
    int stg_src = srow32 * HID + ((((tid & 15) * 16) ^ ((srow32 & 7) << 4)) >> 1);

#define STAGE(buf, tt)                                                        \
    {                                                                         \
        const unsigned short* gs = ub + (size_t)(tt) * 16384 + stg_src;       \
        char* ls = &sU[buf][tid * 16];                                        \
        _Pragma("unroll")                                                     \
        for (int q = 0; q < 4; ++q)                                           \
            gload16(gs + q * 4096, ls + q * 8192);                            \
    }

    // ---- prologue: stage tile 0, drain ----
    STAGE(0, 0)
    __syncthreads();
    int cur = 0;

    // store geometry: lane's 4 rows start at colb; u32 column = pcol
    int colb = wl * 32 + comp * 16 + g * 4;

    for (int t = 0; t < 16; ++t) {
        int l0t = t * 128;

        if (t < 15) STAGE(cur ^ 1, t + 1)

        // ---- GEMM: wave rows wl*32..wl*32+31; B packs [re|im];
        //      2 independent 4-deep MFMA chains per mi ----
        const char* su = &sU[cur][0];
        f32x4 accA[2], accB[2];
        accA[0] = (f32x4)(0.f); accA[1] = (f32x4)(0.f);
        accB[0] = (f32x4)(0.f); accB[1] = (f32x4)(0.f);
#pragma unroll
        for (int kc = 0; kc < 2; ++kc) {
#pragma unroll
            for (int mi = 0; mi < 2; ++mi) {
                int off0 = (wl * 32 + mi * 16 + fr) * 256 + ((kc * 64 + g * 16) ^ ((fr & 7) << 4));
                int off1 = (wl * 32 + mi * 16 + fr) * 256 + (((kc + 2) * 64 + g * 16) ^ ((fr & 7) << 4));
                bf16x8 ah0 = *(const bf16x8*)(su + off0);
                bf16x8 ah1 = *(const bf16x8*)(su + off1);
                accA[mi] = __builtin_amdgcn_mfma_f32_16x16x32_bf16(ah0, Bfh[kc], accA[mi], 0, 0, 0);
                accA[mi] = __builtin_amdgcn_mfma_f32_16x16x32_bf16(ah0, Bfl[kc], accA[mi], 0, 0, 0);
                accB[mi] = __builtin_amdgcn_mfma_f32_16x16x32_bf16(ah1, Bfh[kc + 2], accB[mi], 0, 0, 0);
                accB[mi] = __builtin_amdgcn_mfma_f32_16x16x32_bf16(ah1, Bfl[kc + 2], accB[mi], 0, 0, 0);
            }
        }
        f32x4 acc[2];
        acc[0] = accA[0] + accB[0];
        acc[1] = accA[1] + accB[1];

        // ---- split swap: each lane keeps ONLY its own mi (= comp) ----
        float xr[4], xi[4];
#pragma unroll
        for (int e = 0; e < 4; ++e) {
            float send = (comp == 0) ? acc[1][e] : acc[0][e];
            float oth  = __shfl_xor(send, 8, 64);
            xr[e] = (comp == 0) ? acc[0][e] : oth;
            xi[e] = (comp == 0) ? oth       : acc[1][e];
        }

        // ---- scan phase 1 (split): quad scan + g-scan on own fragment ----
        float Er, Ei, Fr, Fi, For, Foi;
        {
            float lr = pw_r[0], li = pw_i[0];
            float cr = 0.f, ci = 0.f;
#pragma unroll
            for (int r = 0; r < 4; ++r) {
                float nr = fmaf(lr, cr, fmaf(-li, ci, xr[r]));
                float ni = fmaf(lr, ci, fmaf(li, cr, xi[r]));
                cr = nr; ci = ni;
                xr[r] = cr; xi[r] = ci;
            }
            float Qr = cr, Qi = ci;
            float ur = __shfl_up(Qr, 16u, 64);
            float ui = __shfl_up(Qi, 16u, 64);
            if (g >= 1) {
                Qr = fmaf(l4r, ur, fmaf(-l4i, ui, Qr));
                Qi = fmaf(l4r, ui, fmaf(l4i, ur, Qi));
            }
            ur = __shfl_up(Qr, 32u, 64);
            ui = __shfl_up(Qi, 32u, 64);
            if (g >= 2) {
                Qr = fmaf(l8r, ur, fmaf(-l8i, ui, Qr));
                Qi = fmaf(l8r, ui, fmaf(l8i, ur, Qi));
            }
            Er = __shfl_up(Qr, 16u, 64);
            Ei = __shfl_up(Qi, 16u, 64);
            if (g == 0) { Er = 0.f; Ei = 0.f; }
            Fr = __shfl(Qr, fr + 48, 64);   // own-frag total carry
            Fi = __shfl(Qi, fr + 48, 64);
            For = __shfl_xor(Fr, 8, 64);    // partner-frag carry
            Foi = __shfl_xor(Fi, 8, 64);
            float Rr = fmaf(l16r, For, fmaf(-l16i, Foi, Fr));
            float Ri = fmaf(l16r, Foi, fmaf(l16i, For, Fi));
            if (g == 0 && fr >= 8) { Rld[t & 1][wl][wp][frp][0] = Rr; Rld[t & 1][wl][wp][frp][1] = Ri; }
        }
        __syncthreads();   // the ONE barrier: Rld[t&1] published; STAGE(t+1)
                           // drained (vmcnt); sU[cur] ds_reads retired.

        // ---- scan phase 2: cross-wave lam^32 chain; own-mi corrections ----
        {
            float Wr = TCr, Wi = TCi;
            float Tr = TCr, Ti = TCi;
#pragma unroll
            for (int w2 = 0; w2 < 4; ++w2) {
                float rr = Rld[t & 1][w2][wp][frp][0], ri = Rld[t & 1][w2][wp][frp][1];
                float nTr = fmaf(l32r, Tr, fmaf(-l32i, Ti, rr));
                float nTi = fmaf(l32r, Ti, fmaf(l32i, Tr, ri));
                Tr = nTr; Ti = nTi;
                if (w2 < wl) {
                    float nWr = fmaf(l32r, Wr, fmaf(-l32i, Wi, rr));
                    float nWi = fmaf(l32r, Wi, fmaf(l32i, Wr, ri));
                    Wr = nWr; Wi = nWi;
                }
            }
            TCr = Tr; TCi = Ti;
            float prr, pri;
            if (comp == 0) { prr = Wr; pri = Wi; }
            else {
                prr = fmaf(l16r, Wr, fmaf(-l16i, Wi, For));
                pri = fmaf(l16r, Wi, fmaf(l16i, Wr, Foi));
            }
            float Mr = fmaf(lg_r, prr, fmaf(-lg_i, pri, Er));
            float Mi = fmaf(lg_r, pri, fmaf(lg_i, prr, Ei));
#pragma unroll
            for (int r = 0; r < 4; ++r) {
                xr[r] = fmaf(pw_r[r], Mr, fmaf(-pw_i[r], Mi, xr[r]));
                xi[r] = fmaf(pw_r[r], Mi, fmaf(pw_i[r], Mr, xi[r]));
            }
        }

        // ---- direct global stores: 4 aligned u32 (re,im) per lane ----
        {
            size_t rowbase = ((size_t)(b * LEN) + l0t + colb) * 512 + pcol * 2;
#pragma unroll
            for (int r = 0; r < 4; ++r)
                *(unsigned int*)&TP[rowbase + (size_t)r * 512] = cvtpk(xr[r], xi[r]);
        }
        cur ^= 1;
    }
#undef STAGE
}

// ---------------------------------------------------------------------------
// K3 v4 (verified R15): flat GEMM, 3 buffers, depth-2 staging, counted
// vmcnt(3) at raw barriers.
// ---------------------------------------------------------------------------
__global__ __launch_bounds__(512, 4) void k3_out(const unsigned short* __restrict__ TP,
                                                 const unsigned short* __restrict__ C2,
                                                 const unsigned short* __restrict__ ubf,
                                                 const float* __restrict__ D,
                                                 float* __restrict__ out) {
    __shared__ __align__(16) char sAB[3][24576];  // A 8KB ([128 l][64B]) | C 16KB ([2 hilo][128 h][64B])

    int d    = blockIdx.x;            // 0..511
    int xcd  = d & 7;
    int rest = d >> 3;                // 0..63
    int lt   = rest & 15;
    int bhi  = rest >> 4;             // 0..3
    int b    = bhi * 8 + xcd;
    int l0   = lt * 128;

    int tid = threadIdx.x;
    int lane = tid & 63, w = tid >> 6;
    int wl = w >> 1, wh = w & 1;
    int fr = lane & 15, g = lane >> 4;

    f32x4 acc[2][4];
#pragma unroll
    for (int mi = 0; mi < 2; ++mi)
#pragma unroll
        for (int ni = 0; ni < 4; ++ni) acc[mi][ni] = (f32x4)(0.f);

    float dv[4];
#pragma unroll
    for (int ni = 0; ni < 4; ++ni) dv[ni] = D[wh * 64 + ni * 16 + fr];

#define STAGE3(buf, cc)                                                       \
    {                                                                         \
        {                                                                     \
            int rw = tid >> 2, sl = tid & 3;                                  \
            gload16(TP + ((size_t)(b * LEN) + l0 + rw) * 512 + (cc) * 32 +    \
                        ((sl ^ (rw & 3)) * 8),                                \
                    &sAB[buf][tid * 16]);                                     \
        }                                                                     \
        _Pragma("unroll")                                                     \
        for (int q = 0; q < 2; ++q) {                                         \
            int dg = tid + q * 512;                                           \
            int hl = dg >> 9, hr = (dg >> 2) & 127, sl = dg & 3;              \
            gload16(C2 + ((size_t)(hl * 128 + hr)) * 512 + (cc) * 32 +        \
                        ((sl ^ (hr & 3)) * 8),                                \
                    &sAB[buf][8192 + dg * 16]);                               \
        }                                                                     \
    }

    STAGE3(0, 0)
    __syncthreads();
    STAGE3(1, 1)

    int cur = 0;
    for (int c = 0; c < 16; ++c) {
        if (c < 14) STAGE3((cur + 2) % 3, c + 2)

        const char* sb = &sAB[cur][0];
        int swz = (g ^ (fr & 3)) * 16;
        bf16x8 af[2];
#pragma unroll
        for (int mi = 0; mi < 2; ++mi) {
            int arow = wl * 32 + mi * 16 + fr;
            af[mi] = *(const bf16x8*)(sb + arow * 64 + swz);
        }
#pragma unroll
        for (int ni = 0; ni < 4; ++ni) {
            int hrow = wh * 64 + ni * 16 + fr;
            bf16x8 ch = *(const bf16x8*)(sb + 8192 + hrow * 64 + swz);
            bf16x8 cl = *(const bf16x8*)(sb + 8192 + 8192 + hrow * 64 + swz);
#pragma unroll
            for (int mi = 0; mi < 2; ++mi) {
                acc[mi][ni] = __builtin_amdgcn_mfma_f32_16x16x32_bf16(af[mi], ch, acc[mi][ni], 0, 0, 0);
                acc[mi][ni] = __builtin_amdgcn_mfma_f32_16x16x32_bf16(af[mi], cl, acc[mi][ni], 0, 0, 0);
            }
        }
        if (c < 14) {
            asm volatile("s_waitcnt vmcnt(3) lgkmcnt(0)" ::: "memory");
        } else {
            asm volatile("s_waitcnt vmcnt(0) lgkmcnt(0)" ::: "memory");
        }
        __builtin_amdgcn_s_barrier();
        __builtin_amdgcn_sched_barrier(0);
        cur = (cur + 1) % 3;
    }
#undef STAGE3

#pragma unroll
    for (int mi = 0; mi < 2; ++mi)
#pragma unroll
        for (int ni = 0; ni < 4; ++ni) {
            int lb = l0 + wl * 32 + mi * 16 + g * 4;
            int h  = wh * 64 + ni * 16 + fr;
#pragma unroll
            for (int r = 0; r < 4; ++r) {
                size_t idx = ((size_t)b * LEN + lb + r) * HID + h;
                out[idx] = acc[mi][ni][r] + bf2f(ubf[idx]) * dv[ni];
            }
        }
}

// ---------------------------------------------------------------------------
// Workspace layout (bytes):
//   [0, 67108864)              TP: states, kappa-interleaved [b][l][512]
//   [67108864, 67110912)       lam (512 f32)
//   [67110912, 67373056)       B split planes (4 x 32768 ushort)
//   [67373056, 67635200)       C2 (2 hilo x 128 h x 512 kappa ushort)
//   [67635200, 84412416)       ubf: u as bf16 [b][l][h]
// ---------------------------------------------------------------------------
extern "C" void kernel_launch(void* const* d_in, const int* in_sizes, int n_in,
                              void* d_out, int out_size, void* d_ws, size_t ws_size,
                              hipStream_t stream) {
    const float* u  = (const float*)d_in[0];
    const float* A  = (const float*)d_in[1];
    const float* G  = (const float*)d_in[2];
    const float* st = (const float*)d_in[3];
    const float* B  = (const float*)d_in[4];
    const float* C  = (const float*)d_in[5];
    const float* D  = (const float*)d_in[6];
    float* out = (float*)d_out;

    char* WS = (char*)d_ws;
    unsigned short* TP  = (unsigned short*)WS;
    float* lam          = (float*)(WS + 67108864);
    unsigned short* Bsp = (unsigned short*)(WS + 67110912);
    unsigned short* C2  = (unsigned short*)(WS + 67373056);
    unsigned short* ubf = (unsigned short*)(WS + 67635200);

    kprep<<<2305, 256, 0, stream>>>(u, B, C, A, G, st, ubf, Bsp, C2, lam);
    k12_fused<<<512, 512, 0, stream>>>(ubf, Bsp, lam, TP);
    k3_out<<<512, 512, 0, stream>>>(TP, C2, ubf, D, out);
}

// Round 17
// 79.231 us; speedup vs baseline: 1.1465x; 1.0010x over previous
//
#include <hip/hip_runtime.h>
#include <hip/hip_bf16.h>
#include <math.h>

#define BATCH 32
#define LEN   2048
#define HID   128
#define SSM   256

#define BPL 32768                     // elements per B-split plane (256*128)

typedef __attribute__((ext_vector_type(4))) float f32x4;
typedef __attribute__((ext_vector_type(8))) short bf16x8;
typedef __attribute__((ext_vector_type(4))) int   i32x4;

// RNE f32->bf16 (bit trick)
static __device__ __forceinline__ unsigned short f2bf(float x) {
    union { float f; unsigned u; } v; v.f = x;
    unsigned r = (v.u + 0x7FFFu + ((v.u >> 16) & 1u)) >> 16;
    return (unsigned short)r;
}
// truncating f32->bf16 (hi term of split; lo captures remainder exactly)
static __device__ __forceinline__ unsigned short f2bf_hi(float x) {
    union { float f; unsigned u; } v; v.f = x;
    return (unsigned short)(v.u >> 16);
}
static __device__ __forceinline__ float bf2f(unsigned short b) {
    union { unsigned u; float f; } v; v.u = ((unsigned)b) << 16;
    return v.f;
}
// packed RNE pair convert -> one u32 (v_cvt_pk_bf16_f32); lo half = first arg
static __device__ __forceinline__ unsigned int cvtpk(float a, float b) {
    __hip_bfloat162 h = __float22bfloat162_rn(float2{a, b});
    union { __hip_bfloat162 h2; unsigned int u; } c; c.h2 = h;
    return c.u;
}
static __device__ __forceinline__ void cmul(float& rr, float& ri,
                                            float ar, float ai, float br, float bi) {
    rr = ar * br - ai * bi;
    ri = ar * bi + ai * br;
}
// async global->LDS 16B (zero VGPR round-trip; vmcnt-counted)
static __device__ __forceinline__ void gload16(const void* g, void* l) {
    __builtin_amdgcn_global_load_lds(
        (const __attribute__((address_space(1))) unsigned int*)g,
        (__attribute__((address_space(3))) unsigned int*)l,
        16, 0, 0);
}

// ---------------------------------------------------------------------------
// KPREP (merged, verified R15/R16): u->ubf convert; B hi/lo split; C2
// kappa-interleave (im NEGATED); lam.
// ---------------------------------------------------------------------------
__global__ __launch_bounds__(256) void kprep(const float* __restrict__ u,
                                             const float* __restrict__ Bm,
                                             const float* __restrict__ Cm,
                                             const float* __restrict__ A,
                                             const float* __restrict__ G,
                                             const float* __restrict__ steps,
                                             unsigned short* __restrict__ ubf,
                                             unsigned short* __restrict__ Bsp,
                                             unsigned short* __restrict__ C2,
                                             float* __restrict__ lam) {
    if (blockIdx.x < 2048) {
        const int total = BATCH * LEN * HID;
        const int stride = 2048 * 256 * 8;
        for (int i = (blockIdx.x * 256 + threadIdx.x) * 8; i < total; i += stride) {
            f32x4 a = *(const f32x4*)&u[i];
            f32x4 c = *(const f32x4*)&u[i + 4];
            i32x4 o;
            o[0] = (int)cvtpk(a[0], a[1]);
            o[1] = (int)cvtpk(a[2], a[3]);
            o[2] = (int)cvtpk(c[0], c[1]);
            o[3] = (int)cvtpk(c[2], c[3]);
            *(i32x4*)&ubf[i] = o;
        }
        return;
    }
    if (blockIdx.x == 2304) {
        int p = threadIdx.x;
        if (p < SSM) {
            float stp   = 1.f / (1.f + expf(-steps[p]));
            float g     = fmaxf(G[p], 0.f);
            float denom = fmaxf(stp * stp, 1e-6f);
            float s     = stp * g;
            float base  = sqrtf(fmaxf(1.f + s, 1e-6f));
            float alow  = (2.f + s - 2.f * base) / denom;
            float ahigh = (2.f + s + 2.f * base) / denom;
            float a     = alow + fmaxf(A[p] - alow, 0.f) - fmaxf(A[p] - ahigh, 0.f);
            float S     = 1.f / (1.f + stp * g);
            float T     = S + 1.f - stp * stp * S * a;
            lam[p]       = 0.5f * T;
            lam[SSM + p] = sqrtf(fmaxf(S - 0.25f * T * T, 0.f));
        }
        return;
    }
    int gidx = (blockIdx.x - 2048) * 256 + threadIdx.x;
    if (gidx < 32768) {
        int p = gidx >> 7, h = gidx & 127;
        float vr = Bm[(size_t)(p * HID + h) * 2];
        float vi = Bm[(size_t)(p * HID + h) * 2 + 1];
        unsigned short hh = f2bf_hi(vr);
        Bsp[0 * BPL + p * HID + h] = hh;
        Bsp[1 * BPL + p * HID + h] = f2bf(vr - bf2f(hh));
        hh = f2bf_hi(vi);
        Bsp[2 * BPL + p * HID + h] = hh;
        Bsp[3 * BPL + p * HID + h] = f2bf(vi - bf2f(hh));
    } else {
        int g2 = gidx - 32768;
        int h = g2 >> 8, p = g2 & 255;
        float vr = Cm[(size_t)(h * SSM + p) * 2];
        float vi = -Cm[(size_t)(h * SSM + p) * 2 + 1];
        unsigned short rh = f2bf_hi(vr);
        unsigned short ih = f2bf_hi(vi);
        size_t rowh = (size_t)h * 512;
        C2[rowh + 2 * p]               = rh;
        C2[rowh + 2 * p + 1]           = ih;
        C2[65536 + rowh + 2 * p]       = f2bf(vr - bf2f(rh));
        C2[65536 + rowh + 2 * p + 1]   = f2bf(vi - bf2f(ih));
    }
}

// ---------------------------------------------------------------------------
// K12 v13: R16's verified split-scan core + R11's skewed schedule (now
// fitting the register budget thanks to the split scan). Per iter t:
//   STAGE(t+2) | GEMM(t+1) issue (setprio) | ph2(t)+direct stores(t) |
//   ph1(t+1) -> Rld[(t+1)&1] | one barrier.
// GEMM's MFMA+ds latency hides under ph2/stores; staged loads span a full
// tile of compute. All hazards barrier-separated (R11 audit + R16 Rld dbuf).
// Arithmetic byte-identical to R16.
// ---------------------------------------------------------------------------
__global__ __launch_bounds__(512, 4) void k12_fused(const unsigned short* __restrict__ ubf,
                                                    const unsigned short* __restrict__ Bsp,
                                                    const float* __restrict__ lam,
                                                    unsigned short* __restrict__ TP) {
    __shared__ __align__(16) char sU[2][32768];   // dbuf: 128 rows x 256B
    __shared__ float Rld[2][4][2][8][2];          // [t&1][wl][wp][p8][re/im]

    int d    = blockIdx.x;           // 0..511
    int xcd  = d & 7;
    int idx  = d >> 3;               // 0..63
    int pt   = idx & 15;             // 16 p-tiles of 16
    int bhi  = idx >> 4;             // 0..3
    int b    = bhi * 8 + xcd;
    int p0   = pt * 16;

    int tid  = threadIdx.x;
    int lane = tid & 63, w = tid >> 6;
    int wl   = w >> 1, wp = w & 1;
    int fr   = lane & 15, g = lane >> 4;
    int frp  = fr & 7;               // p-column within octet
    int comp = fr >> 3;              // 0 = re-half (owns mi=0), 1 = im-half (owns mi=1)
    int pcol = p0 + wp * 8 + frp;    // this lane's p

    // ---- B fragments: lane's comp & p-col, hi/lo x 4 k-chunks ----
    const unsigned short* Bh  = Bsp + (size_t)(comp * 2) * BPL + (size_t)pcol * HID;
    const unsigned short* Blo = Bsp + (size_t)(comp * 2 + 1) * BPL + (size_t)pcol * HID;
    bf16x8 Bfh[4], Bfl[4];
#pragma unroll
    for (int kc = 0; kc < 4; ++kc) {
        Bfh[kc] = *(const bf16x8*)&Bh[kc * 32 + g * 8];
        Bfl[kc] = *(const bf16x8*)&Blo[kc * 32 + g * 8];
    }

    // ---- lambda powers for p = pcol ----
    float pw_r[4], pw_i[4];          // lam^(r+1)
    float lg_r, lg_i;                // lam^(4g)
    float l4r, l4i, l8r, l8i, l16r, l16i, l32r, l32i;
    {
        float ar = lam[pcol], ai = lam[SSM + pcol];
        pw_r[0] = ar; pw_i[0] = ai;
        cmul(pw_r[1], pw_i[1], ar, ai, ar, ai);
        cmul(pw_r[2], pw_i[2], pw_r[1], pw_i[1], ar, ai);
        cmul(pw_r[3], pw_i[3], pw_r[1], pw_i[1], pw_r[1], pw_i[1]);
        l4r = pw_r[3]; l4i = pw_i[3];
        cmul(l8r, l8i, l4r, l4i, l4r, l4i);
        cmul(l16r, l16i, l8r, l8i, l8r, l8i);
        cmul(l32r, l32i, l16r, l16i, l16r, l16i);
        if (g == 0)      { lg_r = 1.f; lg_i = 0.f; }
        else if (g == 1) { lg_r = l4r; lg_i = l4i; }
        else if (g == 2) { lg_r = l8r; lg_i = l8i; }
        else             { cmul(lg_r, lg_i, l8r, l8i, l4r, l4i); }
    }

    float TCr = 0.f, TCi = 0.f;      // running tile carry (per wp group)

    const unsigned short* ub = ubf + (size_t)b * (LEN * HID);
    int srow32  = tid >> 4;          // 0..31
    int stg_src = srow32 * HID + ((((tid & 15) * 16) ^ ((srow32 & 7) << 4)) >> 1);

#define STAGE(buf, tt)                                                        \
    {                                                                         \
        const unsigned short* gs = ub + (size_t)(tt) * 16384 + stg_src;       \
        char* ls = &sU[buf][tid * 16];                                        \
        _Pragma("unroll")                                                     \
        for (int q = 0; q < 4; ++q)                                           \
            gload16(gs + q * 4096, ls + q * 8192);                            \
    }

    // cross-iteration scan state (split-scan: small)
    float xr[4], xi[4];
    float Er, Ei, For, Foi;

    // GEMM: issue 16 MFMAs from sU[bufidx]; 2 independent 4-chains per mi
#define DO_GEMM(bufidx)                                                       \
    {                                                                         \
        const char* su = &sU[bufidx][0];                                      \
        accA[0] = (f32x4)(0.f); accA[1] = (f32x4)(0.f);                       \
        accB[0] = (f32x4)(0.f); accB[1] = (f32x4)(0.f);                       \
        __builtin_amdgcn_s_setprio(1);                                        \
        _Pragma("unroll")                                                     \
        for (int kc = 0; kc < 2; ++kc) {                                      \
            _Pragma("unroll")                                                 \
            for (int mi = 0; mi < 2; ++mi) {                                  \
                int off0 = (wl * 32 + mi * 16 + fr) * 256 +                   \
                           ((kc * 64 + g * 16) ^ ((fr & 7) << 4));            \
                int off1 = (wl * 32 + mi * 16 + fr) * 256 +                   \
                           (((kc + 2) * 64 + g * 16) ^ ((fr & 7) << 4));      \
                bf16x8 ah0 = *(const bf16x8*)(su + off0);                     \
                bf16x8 ah1 = *(const bf16x8*)(su + off1);                     \
                accA[mi] = __builtin_amdgcn_mfma_f32_16x16x32_bf16(ah0, Bfh[kc], accA[mi], 0, 0, 0);     \
                accA[mi] = __builtin_amdgcn_mfma_f32_16x16x32_bf16(ah0, Bfl[kc], accA[mi], 0, 0, 0);     \
                accB[mi] = __builtin_amdgcn_mfma_f32_16x16x32_bf16(ah1, Bfh[kc + 2], accB[mi], 0, 0, 0); \
                accB[mi] = __builtin_amdgcn_mfma_f32_16x16x32_bf16(ah1, Bfl[kc + 2], accB[mi], 0, 0, 0); \
            }                                                                 \
        }                                                                     \
        __builtin_amdgcn_s_setprio(0);                                        \
    }

    // PH1: consume accA/accB -> xr/xi local scans, Er/Ei/For/Foi, Rld[rb]
#define DO_PH1(rb)                                                            \
    {                                                                         \
        f32x4 acc0 = accA[0] + accB[0];                                       \
        f32x4 acc1 = accA[1] + accB[1];                                       \
        _Pragma("unroll")                                                     \
        for (int e = 0; e < 4; ++e) {                                         \
            float send = (comp == 0) ? acc1[e] : acc0[e];                     \
            float oth  = __shfl_xor(send, 8, 64);                             \
            xr[e] = (comp == 0) ? acc0[e] : oth;                              \
            xi[e] = (comp == 0) ? oth     : acc1[e];                          \
        }                                                                     \
        float lr = pw_r[0], li = pw_i[0];                                     \
        float cr = 0.f, ci = 0.f;                                             \
        _Pragma("unroll")                                                     \
        for (int r = 0; r < 4; ++r) {                                         \
            float nr = fmaf(lr, cr, fmaf(-li, ci, xr[r]));                    \
            float ni = fmaf(lr, ci, fmaf(li, cr, xi[r]));                     \
            cr = nr; ci = ni;                                                 \
            xr[r] = cr; xi[r] = ci;                                           \
        }                                                                     \
        float Qr = cr, Qi = ci;                                               \
        float ur = __shfl_up(Qr, 16u, 64);                                    \
        float ui = __shfl_up(Qi, 16u, 64);                                    \
        if (g >= 1) {                                                         \
            Qr = fmaf(l4r, ur, fmaf(-l4i, ui, Qr));                           \
            Qi = fmaf(l4r, ui, fmaf(l4i, ur, Qi));                            \
        }                                                                     \
        ur = __shfl_up(Qr, 32u, 64);                                          \
        ui = __shfl_up(Qi, 32u, 64);                                          \
        if (g >= 2) {                                                         \
            Qr = fmaf(l8r, ur, fmaf(-l8i, ui, Qr));                           \
            Qi = fmaf(l8r, ui, fmaf(l8i, ur, Qi));                            \
        }                                                                     \
        Er = __shfl_up(Qr, 16u, 64);                                          \
        Ei = __shfl_up(Qi, 16u, 64);                                          \
        if (g == 0) { Er = 0.f; Ei = 0.f; }                                   \
        float Fr = __shfl(Qr, fr + 48, 64);                                   \
        float Fi = __shfl(Qi, fr + 48, 64);                                   \
        For = __shfl_xor(Fr, 8, 64);                                          \
        Foi = __shfl_xor(Fi, 8, 64);                                          \
        float Rr = fmaf(l16r, For, fmaf(-l16i, Foi, Fr));                     \
        float Ri = fmaf(l16r, Foi, fmaf(l16i, For, Fi));                      \
        if (g == 0 && fr >= 8) { Rld[rb][wl][wp][frp][0] = Rr; Rld[rb][wl][wp][frp][1] = Ri; } \
    }

    int colb = wl * 32 + comp * 16 + g * 4;
    f32x4 accA[2], accB[2];

    // ---- prologue ----
    STAGE(0, 0)
    __syncthreads();                  // drain tile 0
    STAGE(1, 1)                       // tile 1 in flight
    DO_GEMM(0)
    DO_PH1(0)
    __syncthreads();                  // drains STAGE(1); publishes Rld[0]

    for (int t = 0; t < 16; ++t) {
        int l0t = t * 128;

        if (t < 14) STAGE(t & 1, t + 2)      // buf retired at bar(t-1)
        if (t < 15) DO_GEMM((t + 1) & 1)     // consumed by PH1 below

        // ---- ph2(t): cross-wave lam^32 chain; own-mi corrections ----
        {
            float Wr = TCr, Wi = TCi;
            float Tr = TCr, Ti = TCi;
#pragma unroll
            for (int w2 = 0; w2 < 4; ++w2) {
                float rr = Rld[t & 1][w2][wp][frp][0], ri = Rld[t & 1][w2][wp][frp][1];
                float nTr = fmaf(l32r, Tr, fmaf(-l32i, Ti, rr));
                float nTi = fmaf(l32r, Ti, fmaf(l32i, Tr, ri));
                Tr = nTr; Ti = nTi;
                if (w2 < wl) {
                    float nWr = fmaf(l32r, Wr, fmaf(-l32i, Wi, rr));
                    float nWi = fmaf(l32r, Wi, fmaf(l32i, Wr, ri));
                    Wr = nWr; Wi = nWi;
                }
            }
            TCr = Tr; TCi = Ti;
            float prr, pri;
            if (comp == 0) { prr = Wr; pri = Wi; }
            else {
                prr = fmaf(l16r, Wr, fmaf(-l16i, Wi, For));
                pri = fmaf(l16r, Wi, fmaf(l16i, Wr, Foi));
            }
            float Mr = fmaf(lg_r, prr, fmaf(-lg_i, pri, Er));
            float Mi = fmaf(lg_r, pri, fmaf(lg_i, prr, Ei));
#pragma unroll
            for (int r = 0; r < 4; ++r) {
                xr[r] = fmaf(pw_r[r], Mr, fmaf(-pw_i[r], Mi, xr[r]));
                xi[r] = fmaf(pw_r[r], Mi, fmaf(pw_i[r], Mr, xi[r]));
            }
        }

        // ---- direct global stores: 4 aligned u32 (re,im) per lane ----
        {
            size_t rowbase = ((size_t)(b * LEN) + l0t + colb) * 512 + pcol * 2;
#pragma unroll
            for (int r = 0; r < 4; ++r)
                *(unsigned int*)&TP[rowbase + (size_t)r * 512] = cvtpk(xr[r], xi[r]);
        }

        if (t < 15) DO_PH1((t + 1) & 1)      // tile t+1 local scans + Rld

        __syncthreads();  // drains STAGE(t+2) vmcnt; publishes Rld[(t+1)&1];
                          // retires GEMM(t+1) ds_reads of buf[(t+1)&1]
    }
#undef STAGE
#undef DO_GEMM
#undef DO_PH1
}

// ---------------------------------------------------------------------------
// K3 v4 (verified R15/R16): flat GEMM, 3 buffers, depth-2 staging, counted
// vmcnt(3) at raw barriers.
// ---------------------------------------------------------------------------
__global__ __launch_bounds__(512, 4) void k3_out(const unsigned short* __restrict__ TP,
                                                 const unsigned short* __restrict__ C2,
                                                 const unsigned short* __restrict__ ubf,
                                                 const float* __restrict__ D,
                                                 float* __restrict__ out) {
    __shared__ __align__(16) char sAB[3][24576];  // A 8KB ([128 l][64B]) | C 16KB ([2 hilo][128 h][64B])

    int d    = blockIdx.x;            // 0..511
    int xcd  = d & 7;
    int rest = d >> 3;                // 0..63
    int lt   = rest & 15;
    int bhi  = rest >> 4;             // 0..3
    int b    = bhi * 8 + xcd;
    int l0   = lt * 128;

    int tid = threadIdx.x;
    int lane = tid & 63, w = tid >> 6;
    int wl = w >> 1, wh = w & 1;
    int fr = lane & 15, g = lane >> 4;

    f32x4 acc[2][4];
#pragma unroll
    for (int mi = 0; mi < 2; ++mi)
#pragma unroll
        for (int ni = 0; ni < 4; ++ni) acc[mi][ni] = (f32x4)(0.f);

    float dv[4];
#pragma unroll
    for (int ni = 0; ni < 4; ++ni) dv[ni] = D[wh * 64 + ni * 16 + fr];

#define STAGE3(buf, cc)                                                       \
    {                                                                         \
        {                                                                     \
            int rw = tid >> 2, sl = tid & 3;                                  \
            gload16(TP + ((size_t)(b * LEN) + l0 + rw) * 512 + (cc) * 32 +    \
                        ((sl ^ (rw & 3)) * 8),                                \
                    &sAB[buf][tid * 16]);                                     \
        }                                                                     \
        _Pragma("unroll")                                                     \
        for (int q = 0; q < 2; ++q) {                                         \
            int dg = tid + q * 512;                                           \
            int hl = dg >> 9, hr = (dg >> 2) & 127, sl = dg & 3;              \
            gload16(C2 + ((size_t)(hl * 128 + hr)) * 512 + (cc) * 32 +        \
                        ((sl ^ (hr & 3)) * 8),                                \
                    &sAB[buf][8192 + dg * 16]);                               \
        }                                                                     \
    }

    STAGE3(0, 0)
    __syncthreads();
    STAGE3(1, 1)

    int cur = 0;
    for (int c = 0; c < 16; ++c) {
        if (c < 14) STAGE3((cur + 2) % 3, c + 2)

        const char* sb = &sAB[cur][0];
        int swz = (g ^ (fr & 3)) * 16;
        bf16x8 af[2];
#pragma unroll
        for (int mi = 0; mi < 2; ++mi) {
            int arow = wl * 32 + mi * 16 + fr;
            af[mi] = *(const bf16x8*)(sb + arow * 64 + swz);
        }
#pragma unroll
        for (int ni = 0; ni < 4; ++ni) {
            int hrow = wh * 64 + ni * 16 + fr;
            bf16x8 ch = *(const bf16x8*)(sb + 8192 + hrow * 64 + swz);
            bf16x8 cl = *(const bf16x8*)(sb + 8192 + 8192 + hrow * 64 + swz);
#pragma unroll
            for (int mi = 0; mi < 2; ++mi) {
                acc[mi][ni] = __builtin_amdgcn_mfma_f32_16x16x32_bf16(af[mi], ch, acc[mi][ni], 0, 0, 0);
                acc[mi][ni] = __builtin_amdgcn_mfma_f32_16x16x32_bf16(af[mi], cl, acc[mi][ni], 0, 0, 0);
            }
        }
        if (c < 14) {
            asm volatile("s_waitcnt vmcnt(3) lgkmcnt(0)" ::: "memory");
        } else {
            asm volatile("s_waitcnt vmcnt(0) lgkmcnt(0)" ::: "memory");
        }
        __builtin_amdgcn_s_barrier();
        __builtin_amdgcn_sched_barrier(0);
        cur = (cur + 1) % 3;
    }
#undef STAGE3

#pragma unroll
    for (int mi = 0; mi < 2; ++mi)
#pragma unroll
        for (int ni = 0; ni < 4; ++ni) {
            int lb = l0 + wl * 32 + mi * 16 + g * 4;
            int h  = wh * 64 + ni * 16 + fr;
#pragma unroll
            for (int r = 0; r < 4; ++r) {
                size_t idx = ((size_t)b * LEN + lb + r) * HID + h;
                out[idx] = acc[mi][ni][r] + bf2f(ubf[idx]) * dv[ni];
            }
        }
}

// ---------------------------------------------------------------------------
// Workspace layout (bytes):
//   [0, 67108864)              TP: states, kappa-interleaved [b][l][512]
//   [67108864, 67110912)       lam (512 f32)
//   [67110912, 67373056)       B split planes (4 x 32768 ushort)
//   [67373056, 67635200)       C2 (2 hilo x 128 h x 512 kappa ushort)
//   [67635200, 84412416)       ubf: u as bf16 [b][l][h]
// ---------------------------------------------------------------------------
extern "C" void kernel_launch(void* const* d_in, const int* in_sizes, int n_in,
                              void* d_out, int out_size, void* d_ws, size_t ws_size,
                              hipStream_t stream) {
    const float* u  = (const float*)d_in[0];
    const float* A  = (const float*)d_in[1];
    const float* G  = (const float*)d_in[2];
    const float* st = (const float*)d_in[3];
    const float* B  = (const float*)d_in[4];
    const float* C  = (const float*)d_in[5];
    const float* D  = (const float*)d_in[6];
    float* out = (float*)d_out;

    char* WS = (char*)d_ws;
    unsigned short* TP  = (unsigned short*)WS;
    float* lam          = (float*)(WS + 67108864);
    unsigned short* Bsp = (unsigned short*)(WS + 67110912);
    unsigned short* C2  = (unsigned short*)(WS + 67373056);
    unsigned short* ubf = (unsigned short*)(WS + 67635200);

    kprep<<<2305, 256, 0, stream>>>(u, B, C, A, G, st, ubf, Bsp, C2, lam);
    k12_fused<<<512, 512, 0, stream>>>(ubf, Bsp, lam, TP);
    k3_out<<<512, 512, 0, stream>>>(TP, C2, ubf, D, out);
}